// Round 1
// baseline (7142.319 us; speedup 1.0000x reference)
//
#include <hip/hip_runtime.h>

#define NN 100000
#define NE 1600000
#define NG 512
#define FIN 64
#define HD 128
#define H3 384
#define NSTEP 6
#define SCHUNK 1024
#define NBLK 98   // ceil(NN/SCHUNK)

__device__ __forceinline__ float sigm(float x) { return 1.f / (1.f + __expf(-x)); }
__device__ __forceinline__ float tanhfast(float x) { return 2.f / (1.f + __expf(-2.f * x)) - 1.f; }

// ---------------- CSR build ----------------
__global__ void k_count(const int* __restrict__ dst, int* __restrict__ counts) {
    int e = blockIdx.x * 256 + threadIdx.x;
    if (e < NE) atomicAdd(&counts[dst[e]], 1);
}

__global__ void k_scan1(const int* __restrict__ counts, int* __restrict__ indptr, int* __restrict__ aux) {
    __shared__ int sh[256];
    int blk = blockIdx.x, tid = threadIdx.x;
    int base = blk * SCHUNK + tid * 4;
    int v0 = 0, v1 = 0, v2 = 0, v3 = 0;
    if (base + 0 < NN) v0 = counts[base + 0];
    if (base + 1 < NN) v1 = counts[base + 1];
    if (base + 2 < NN) v2 = counts[base + 2];
    if (base + 3 < NN) v3 = counts[base + 3];
    int tsum = v0 + v1 + v2 + v3;
    sh[tid] = tsum;
    __syncthreads();
    for (int off = 1; off < 256; off <<= 1) {
        int t = (tid >= off) ? sh[tid - off] : 0;
        __syncthreads();
        sh[tid] += t;
        __syncthreads();
    }
    int excl = sh[tid] - tsum;
    if (base + 0 < NN) indptr[base + 0] = excl;
    if (base + 1 < NN) indptr[base + 1] = excl + v0;
    if (base + 2 < NN) indptr[base + 2] = excl + v0 + v1;
    if (base + 3 < NN) indptr[base + 3] = excl + v0 + v1 + v2;
    if (tid == 255) aux[blk] = sh[255];
}

__global__ void k_scan2(int* __restrict__ aux) {
    __shared__ int sh[128];
    int tid = threadIdx.x;
    int v = (tid < NBLK) ? aux[tid] : 0;
    sh[tid] = v;
    __syncthreads();
    for (int off = 1; off < 128; off <<= 1) {
        int t = (tid >= off) ? sh[tid - off] : 0;
        __syncthreads();
        sh[tid] += t;
        __syncthreads();
    }
    if (tid < NBLK) aux[tid] = sh[tid] - v;   // exclusive block offsets
}

__global__ void k_scan3(int* __restrict__ indptr, int* __restrict__ cursor, const int* __restrict__ aux) {
    int blk = blockIdx.x, tid = threadIdx.x;
    int off = aux[blk];
    int base = blk * SCHUNK + tid * 4;
#pragma unroll
    for (int i = 0; i < 4; ++i) {
        int idx = base + i;
        if (idx < NN) {
            int v = indptr[idx] + off;
            indptr[idx] = v;
            cursor[idx] = v;
        }
    }
    if (blk == 0 && tid == 0) indptr[NN] = NE;
}

__global__ void k_fill(const int* __restrict__ src, const int* __restrict__ dst,
                       int* __restrict__ cursor, int* __restrict__ csr) {
    int e = blockIdx.x * 256 + threadIdx.x;
    if (e < NE) {
        int d = dst[e];
        int p = atomicAdd(&cursor[d], 1);
        csr[p] = src[e];
    }
}

// ---------------- W_eff[s] = W_mp[s] @ W_ih^T, stored transposed [s][j][k] ----------------
__global__ void k_weff(const float* __restrict__ Wmp, const float* __restrict__ Wih,
                       float* __restrict__ WeffT) {
    __shared__ float wih[HD];
    int s = blockIdx.x / H3;
    int j = blockIdx.x % H3;
    int k = threadIdx.x;  // 128 threads
    wih[k] = Wih[(size_t)j * HD + k];
    __syncthreads();
    const float* wm = Wmp + ((size_t)s * HD + k) * HD;
    float acc = 0.f;
#pragma unroll 8
    for (int t = 0; t < HD; ++t) acc += wm[t] * wih[t];
    WeffT[((size_t)s * H3 + j) * HD + k] = acc;
}

// ---------------- input layer: h = tanh(x @ W_in) ----------------
__global__ void k_input(const float* __restrict__ x, const float* __restrict__ Win,
                        float* __restrict__ h) {
    __shared__ float xs[2][FIN];
    int half = threadIdx.x >> 7;            // 0/1: which node of this block
    int j = threadIdx.x & 127;
    int node = blockIdx.x * 2 + half;
    if (j < FIN) xs[half][j] = x[(size_t)node * FIN + j];
    __syncthreads();
    float acc = 0.f;
#pragma unroll 8
    for (int k = 0; k < FIN; ++k) acc += xs[half][k] * Win[(size_t)k * HD + j];
    h[(size_t)node * HD + j] = tanhfast(acc);
}

// ---------------- aggregation: S[v] = sum_{in-edges} h[src] ----------------
__global__ void k_agg(const float* __restrict__ h, const int* __restrict__ indptr,
                      const int* __restrict__ csr, float* __restrict__ S) {
    int v = blockIdx.x * 4 + (threadIdx.x >> 6);
    int lane = threadIdx.x & 63;
    int s = indptr[v], e = indptr[v + 1];
    float2 acc = make_float2(0.f, 0.f);
    for (int i = s; i < e; ++i) {
        int u = csr[i];
        float2 t = ((const float2*)(h + (size_t)u * HD))[lane];
        acc.x += t.x;
        acc.y += t.y;
    }
    ((float2*)(S + (size_t)v * HD))[lane] = acc;
}

// ---------------- fused GRU: gi = S@W_eff + b_ih ; gh = h@W_hh^T + b_hh ; gates ----------------
// Out may alias S (tile is read into LDS before any write).
__global__ void __launch_bounds__(256) k_gru(const float* __restrict__ S, const float* __restrict__ Hm,
                                             const float* __restrict__ WeffT_s, const float* __restrict__ Whh,
                                             const float* __restrict__ bih, const float* __restrict__ bhh,
                                             float* __restrict__ Out) {
    __shared__ float As[16 * HD];
    __shared__ float Ah[16 * HD];
    int tid = threadIdx.x;
    int row0 = blockIdx.x * 16;
    {
        const float4* Sg = (const float4*)(S + (size_t)row0 * HD);
        const float4* Hg = (const float4*)(Hm + (size_t)row0 * HD);
        float4* As4 = (float4*)As;
        float4* Ah4 = (float4*)Ah;
        for (int i = tid; i < 16 * HD / 4; i += 256) {
            As4[i] = Sg[i];
            Ah4[i] = Hg[i];
        }
    }
    __syncthreads();

    int tr = tid & 127;        // gate-triple (output column within H)
    int rh = tid >> 7;         // row half: rows rh*8 .. rh*8+7
    const float4* w0 = (const float4*)(WeffT_s + (size_t)tr * HD);
    const float4* w1 = (const float4*)(WeffT_s + (size_t)(tr + 128) * HD);
    const float4* w2 = (const float4*)(WeffT_s + (size_t)(tr + 256) * HD);
    const float4* u0 = (const float4*)(Whh + (size_t)tr * HD);
    const float4* u1 = (const float4*)(Whh + (size_t)(tr + 128) * HD);
    const float4* u2 = (const float4*)(Whh + (size_t)(tr + 256) * HD);

    float gi0[8], gi1[8], gi2[8], gh0[8], gh1[8], gh2[8];
#pragma unroll
    for (int r = 0; r < 8; ++r) { gi0[r] = gi1[r] = gi2[r] = gh0[r] = gh1[r] = gh2[r] = 0.f; }

    const float4* As4 = (const float4*)(As + (size_t)rh * 8 * HD);
    const float4* Ah4 = (const float4*)(Ah + (size_t)rh * 8 * HD);

    for (int kk = 0; kk < HD / 4; ++kk) {
        float4 W0 = w0[kk], W1 = w1[kk], W2 = w2[kk];
        float4 U0 = u0[kk], U1 = u1[kk], U2 = u2[kk];
#pragma unroll
        for (int r = 0; r < 8; ++r) {
            float4 a = As4[r * (HD / 4) + kk];
            float4 b = Ah4[r * (HD / 4) + kk];
            gi0[r] += a.x * W0.x + a.y * W0.y + a.z * W0.z + a.w * W0.w;
            gi1[r] += a.x * W1.x + a.y * W1.y + a.z * W1.z + a.w * W1.w;
            gi2[r] += a.x * W2.x + a.y * W2.y + a.z * W2.z + a.w * W2.w;
            gh0[r] += b.x * U0.x + b.y * U0.y + b.z * U0.z + b.w * U0.w;
            gh1[r] += b.x * U1.x + b.y * U1.y + b.z * U1.z + b.w * U1.w;
            gh2[r] += b.x * U2.x + b.y * U2.y + b.z * U2.z + b.w * U2.w;
        }
    }

    float bir = bih[tr], biz = bih[tr + 128], binn = bih[tr + 256];
    float bhr = bhh[tr], bhz = bhh[tr + 128], bhn = bhh[tr + 256];
#pragma unroll
    for (int r = 0; r < 8; ++r) {
        float ir = gi0[r] + bir, iz = gi1[r] + biz, inn = gi2[r] + binn;
        float hr = gh0[r] + bhr, hz = gh1[r] + bhz, hn = gh2[r] + bhn;
        float rg = sigm(ir + hr);
        float zg = sigm(iz + hz);
        float ng = tanhfast(inn + rg * hn);
        float ho = Ah[(rh * 8 + r) * HD + tr];
        Out[(size_t)(row0 + rh * 8 + r) * HD + tr] = (1.f - zg) * ng + zg * ho;
    }
}

// ---------------- pooling + head ----------------
__global__ void k_ginit(int* __restrict__ gs, int* __restrict__ ge) {
    int g = threadIdx.x;
    if (g < NG) { gs[g] = 0; ge[g] = 0; }
}

__global__ void k_bounds(const int* __restrict__ batch, int* __restrict__ gs, int* __restrict__ ge) {
    int i = blockIdx.x * 256 + threadIdx.x;
    if (i >= NN) return;
    int b = batch[i];
    if (i == 0 || batch[i - 1] != b) gs[b] = i;
    if (i == NN - 1 || batch[i + 1] != b) ge[b] = i + 1;
}

__global__ void k_pool(const float* __restrict__ h, const int* __restrict__ gs, const int* __restrict__ ge,
                       const float* __restrict__ Wp, const float* __restrict__ bp, float* __restrict__ out) {
    __shared__ float red[HD];
    int g = blockIdx.x, tid = threadIdx.x;
    int s = gs[g], e = ge[g];
    float acc = 0.f;
    for (int n = s; n < e; ++n) acc += h[(size_t)n * HD + tid];
    int cnt = e - s;
    float pooled = acc / (float)(cnt > 0 ? cnt : 1);
    red[tid] = fmaxf(pooled, 0.f) * Wp[tid];
    __syncthreads();
    for (int off = 64; off > 0; off >>= 1) {
        if (tid < off) red[tid] += red[tid + off];
        __syncthreads();
    }
    if (tid == 0) out[g] = red[0] + bp[0];
}

extern "C" void kernel_launch(void* const* d_in, const int* in_sizes, int n_in,
                              void* d_out, int out_size, void* d_ws, size_t ws_size,
                              hipStream_t stream) {
    const float* x   = (const float*)d_in[0];
    const int*   ei  = (const int*)d_in[1];
    const int*   bat = (const int*)d_in[2];
    const float* Win = (const float*)d_in[3];
    const float* Wmp = (const float*)d_in[4];
    const float* Wih = (const float*)d_in[5];
    const float* Whh = (const float*)d_in[6];
    const float* bih = (const float*)d_in[7];
    const float* bhh = (const float*)d_in[8];
    const float* Wp  = (const float*)d_in[9];
    const float* bp  = (const float*)d_in[10];
    float* out = (float*)d_out;

    const int* esrc = ei;
    const int* edst = ei + NE;

    char* w = (char*)d_ws;
    float* bufA  = (float*)w; w += (size_t)NN * HD * 4;
    float* bufB  = (float*)w; w += (size_t)NN * HD * 4;
    float* WeffT = (float*)w; w += (size_t)NSTEP * H3 * HD * 4;
    int* indptr  = (int*)w;   w += (size_t)(NN + 1) * 4;
    int* cursor  = (int*)w;   w += (size_t)NN * 4;
    int* csr     = (int*)w;   w += (size_t)NE * 4;
    int* aux     = (int*)w;   w += 128 * 4;
    int* gs      = (int*)w;   w += NG * 4;
    int* ge      = (int*)w;   w += NG * 4;

    // CSR build (once per call)
    hipMemsetAsync(cursor, 0, (size_t)NN * 4, stream);
    k_count<<<NE / 256, 256, 0, stream>>>(edst, cursor);
    k_scan1<<<NBLK, 256, 0, stream>>>(cursor, indptr, aux);
    k_scan2<<<1, 128, 0, stream>>>(aux);
    k_scan3<<<NBLK, 256, 0, stream>>>(indptr, cursor, aux);
    k_fill<<<NE / 256, 256, 0, stream>>>(esrc, edst, cursor, csr);

    // W_eff precompute + input layer
    k_weff<<<NSTEP * H3, 128, 0, stream>>>(Wmp, Wih, WeffT);
    k_input<<<NN / 2, 256, 0, stream>>>(x, Win, bufA);

    // 6 message-passing + GRU steps (ping-pong between bufA/bufB)
    float* h = bufA;
    float* s = bufB;
    for (int st = 0; st < NSTEP; ++st) {
        k_agg<<<NN / 4, 256, 0, stream>>>(h, indptr, csr, s);
        k_gru<<<NN / 16, 256, 0, stream>>>(s, h, WeffT + (size_t)st * H3 * HD, Whh, bih, bhh, s);
        float* t = h; h = s; s = t;
    }

    // graph ranges + pool + head
    k_ginit<<<1, NG, 0, stream>>>(gs, ge);
    k_bounds<<<(NN + 255) / 256, 256, 0, stream>>>(bat, gs, ge);
    k_pool<<<NG, HD, 0, stream>>>(h, gs, ge, Wp, bp, out);
}

// Round 2
// 2991.104 us; speedup vs baseline: 2.3879x; 2.3879x over previous
//
#include <hip/hip_runtime.h>

#define NN 100000
#define NE 1600000
#define NG 512
#define FIN 64
#define HD 128
#define H3 384
#define NSTEP 6
#define SCHUNK 1024
#define NBLK 98   // ceil(NN/SCHUNK)

typedef _Float16 f16x8 __attribute__((ext_vector_type(8)));
typedef _Float16 f16x2 __attribute__((ext_vector_type(2)));
typedef float    f32x4 __attribute__((ext_vector_type(4)));

__device__ __forceinline__ float sigm(float x) { return 1.f / (1.f + __expf(-x)); }
__device__ __forceinline__ float tanhfast(float x) { return 2.f / (1.f + __expf(-2.f * x)) - 1.f; }

// ---------------- CSR build ----------------
__global__ void k_count(const int* __restrict__ dst, int* __restrict__ counts) {
    int e = blockIdx.x * 256 + threadIdx.x;
    if (e < NE) atomicAdd(&counts[dst[e]], 1);
}

__global__ void k_scan1(const int* __restrict__ counts, int* __restrict__ indptr, int* __restrict__ aux) {
    __shared__ int sh[256];
    int blk = blockIdx.x, tid = threadIdx.x;
    int base = blk * SCHUNK + tid * 4;
    int v0 = 0, v1 = 0, v2 = 0, v3 = 0;
    if (base + 0 < NN) v0 = counts[base + 0];
    if (base + 1 < NN) v1 = counts[base + 1];
    if (base + 2 < NN) v2 = counts[base + 2];
    if (base + 3 < NN) v3 = counts[base + 3];
    int tsum = v0 + v1 + v2 + v3;
    sh[tid] = tsum;
    __syncthreads();
    for (int off = 1; off < 256; off <<= 1) {
        int t = (tid >= off) ? sh[tid - off] : 0;
        __syncthreads();
        sh[tid] += t;
        __syncthreads();
    }
    int excl = sh[tid] - tsum;
    if (base + 0 < NN) indptr[base + 0] = excl;
    if (base + 1 < NN) indptr[base + 1] = excl + v0;
    if (base + 2 < NN) indptr[base + 2] = excl + v0 + v1;
    if (base + 3 < NN) indptr[base + 3] = excl + v0 + v1 + v2;
    if (tid == 255) aux[blk] = sh[255];
}

__global__ void k_scan2(int* __restrict__ aux) {
    __shared__ int sh[128];
    int tid = threadIdx.x;
    int v = (tid < NBLK) ? aux[tid] : 0;
    sh[tid] = v;
    __syncthreads();
    for (int off = 1; off < 128; off <<= 1) {
        int t = (tid >= off) ? sh[tid - off] : 0;
        __syncthreads();
        sh[tid] += t;
        __syncthreads();
    }
    if (tid < NBLK) aux[tid] = sh[tid] - v;   // exclusive block offsets
}

__global__ void k_scan3(int* __restrict__ indptr, int* __restrict__ cursor, const int* __restrict__ aux) {
    int blk = blockIdx.x, tid = threadIdx.x;
    int off = aux[blk];
    int base = blk * SCHUNK + tid * 4;
#pragma unroll
    for (int i = 0; i < 4; ++i) {
        int idx = base + i;
        if (idx < NN) {
            int v = indptr[idx] + off;
            indptr[idx] = v;
            cursor[idx] = v;
        }
    }
    if (blk == 0 && tid == 0) indptr[NN] = NE;
}

__global__ void k_fill(const int* __restrict__ src, const int* __restrict__ dst,
                       int* __restrict__ cursor, int* __restrict__ csr) {
    int e = blockIdx.x * 256 + threadIdx.x;
    if (e < NE) {
        int d = dst[e];
        int p = atomicAdd(&cursor[d], 1);
        csr[p] = src[e];
    }
}

// ---------------- B-matrix prep: Bcat[s][c][k] (c=0..511, k=0..255), fp16 hi/lo ----------------
// c: gate g = c>>7 (0=r_pre, 1=z_pre, 2=i_n, 3=h_n), j = c&127.
// k<128:  g!=3 ? Weff[s][k][jj]  (= dot(Wmp[s][k][:], Wih[jj][:]))  : 0
// k>=128: g!=2 ? Whh[jj][k-128] : 0
__global__ void k_prepB(const float* __restrict__ Wmp, const float* __restrict__ Wih,
                        const float* __restrict__ Whh,
                        _Float16* __restrict__ Bhi, _Float16* __restrict__ Blo) {
    __shared__ float wih[HD];
    int b = blockIdx.x;          // s*512 + c
    int s = b >> 9;
    int c = b & 511;
    int g = c >> 7;
    int j = c & 127;
    int jj = (g < 2) ? c : (j + 256);
    int k = threadIdx.x;         // 0..255
    if (k < HD) wih[k] = Wih[(size_t)jj * HD + k];
    __syncthreads();
    float val = 0.f;
    if (k < 128) {
        if (g != 3) {
            const float* wm = Wmp + ((size_t)s * HD + k) * HD;
            float acc = 0.f;
#pragma unroll 8
            for (int t = 0; t < HD; ++t) acc += wm[t] * wih[t];
            val = acc;
        }
    } else {
        if (g != 2) val = Whh[(size_t)jj * HD + (k - 128)];
    }
    _Float16 hi = (_Float16)val;
    size_t idx = (size_t)b * 256 + k;
    Bhi[idx] = hi;
    Blo[idx] = (_Float16)(val - (float)hi);
}

// ---------------- input layer: h = tanh(x @ W_in), stored fp16 hi/lo ----------------
__global__ void k_input(const float* __restrict__ x, const float* __restrict__ Win,
                        _Float16* __restrict__ Hhi, _Float16* __restrict__ Hlo) {
    __shared__ float xs[2][FIN];
    int half = threadIdx.x >> 7;
    int j = threadIdx.x & 127;
    int node = blockIdx.x * 2 + half;
    if (j < FIN) xs[half][j] = x[(size_t)node * FIN + j];
    __syncthreads();
    float acc = 0.f;
#pragma unroll 8
    for (int k = 0; k < FIN; ++k) acc += xs[half][k] * Win[(size_t)k * HD + j];
    float v = tanhfast(acc);
    _Float16 hi = (_Float16)v;
    size_t idx = (size_t)node * HD + j;
    Hhi[idx] = hi;
    Hlo[idx] = (_Float16)(v - (float)hi);
}

// ---------------- aggregation: S[v] = sum_{in-edges} (Hhi+Hlo)[src], stored fp16 hi/lo ----------------
__global__ void k_agg(const _Float16* __restrict__ Hhi, const _Float16* __restrict__ Hlo,
                      const int* __restrict__ indptr, const int* __restrict__ csr,
                      _Float16* __restrict__ Shi, _Float16* __restrict__ Slo) {
    int v = blockIdx.x * 4 + (threadIdx.x >> 6);
    int lane = threadIdx.x & 63;
    int s = indptr[v], e = indptr[v + 1];
    float ax = 0.f, ay = 0.f;
    for (int i = s; i < e; ++i) {
        int u = csr[i];
        f16x2 th = *(const f16x2*)(Hhi + (size_t)u * HD + lane * 2);
        f16x2 tl = *(const f16x2*)(Hlo + (size_t)u * HD + lane * 2);
        ax += (float)th.x + (float)tl.x;
        ay += (float)th.y + (float)tl.y;
    }
    f16x2 oh, ol;
    oh.x = (_Float16)ax; ol.x = (_Float16)(ax - (float)oh.x);
    oh.y = (_Float16)ay; ol.y = (_Float16)(ay - (float)oh.y);
    size_t idx = (size_t)v * HD + lane * 2;
    *(f16x2*)(Shi + idx) = oh;
    *(f16x2*)(Slo + idx) = ol;
}

// ---------------- fused MFMA GEMM + GRU gates ----------------
// A = [S | H] (100000 x 256, fp16 hi/lo), B = Bcat (256 x 512, fp16 hi/lo).
// Block: 32 rows, 256 threads = 4 waves. Wave w owns j-range [w*32, w*32+32) across all
// 4 gate groups -> 8 N-subtiles of 16, x2 M-subtiles. 3-product fp16-split MFMA.
// H updated IN PLACE (each block touches only its own 32 rows).
__global__ void __launch_bounds__(256) k_ggemm(
        const _Float16* __restrict__ Shi, const _Float16* __restrict__ Slo,
        _Float16* __restrict__ Hhi, _Float16* __restrict__ Hlo,
        const _Float16* __restrict__ Bhi, const _Float16* __restrict__ Blo,
        const float* __restrict__ bih, const float* __restrict__ bhh) {
    int tid = threadIdx.x;
    int w = tid >> 6, lane = tid & 63;
    int quad = lane >> 4, l16 = lane & 15;
    int m0 = blockIdx.x * 32;

    f32x4 acc[2][8];
#pragma unroll
    for (int mi = 0; mi < 2; ++mi)
#pragma unroll
        for (int t = 0; t < 8; ++t) acc[mi][t] = (f32x4){0.f, 0.f, 0.f, 0.f};

    size_t arow0 = (size_t)(m0 + l16) * HD;
    size_t arow1 = (size_t)(m0 + 16 + l16) * HD;

    for (int kt = 0; kt < 8; ++kt) {
        const _Float16* Ahi_b = (kt < 4) ? Shi : Hhi;
        const _Float16* Alo_b = (kt < 4) ? Slo : Hlo;
        int ko = (kt & 3) * 32 + quad * 8;
        f16x8 a_hi0 = *(const f16x8*)(Ahi_b + arow0 + ko);
        f16x8 a_hi1 = *(const f16x8*)(Ahi_b + arow1 + ko);
        f16x8 a_lo0 = *(const f16x8*)(Alo_b + arow0 + ko);
        f16x8 a_lo1 = *(const f16x8*)(Alo_b + arow1 + ko);
#pragma unroll
        for (int t = 0; t < 8; ++t) {
            int cbase = ((t >> 1) << 7) + w * 32 + ((t & 1) << 4);
            size_t boff = (size_t)(cbase + l16) * 256 + kt * 32 + quad * 8;
            f16x8 b_hi = *(const f16x8*)(Bhi + boff);
            f16x8 b_lo = *(const f16x8*)(Blo + boff);
            acc[0][t] = __builtin_amdgcn_mfma_f32_16x16x32_f16(a_hi0, b_hi, acc[0][t], 0, 0, 0);
            acc[0][t] = __builtin_amdgcn_mfma_f32_16x16x32_f16(a_hi0, b_lo, acc[0][t], 0, 0, 0);
            acc[0][t] = __builtin_amdgcn_mfma_f32_16x16x32_f16(a_lo0, b_hi, acc[0][t], 0, 0, 0);
            acc[1][t] = __builtin_amdgcn_mfma_f32_16x16x32_f16(a_hi1, b_hi, acc[1][t], 0, 0, 0);
            acc[1][t] = __builtin_amdgcn_mfma_f32_16x16x32_f16(a_hi1, b_lo, acc[1][t], 0, 0, 0);
            acc[1][t] = __builtin_amdgcn_mfma_f32_16x16x32_f16(a_lo1, b_hi, acc[1][t], 0, 0, 0);
        }
    }

    // epilogue: gates, fully wave-local. C/D layout: col = lane&15, row = quad*4 + reg.
#pragma unroll
    for (int ns = 0; ns < 2; ++ns) {
        int j = w * 32 + ns * 16 + l16;
        float br  = bih[j]       + bhh[j];
        float bz  = bih[j + 128] + bhh[j + 128];
        float bin = bih[j + 256];
        float bhn = bhh[j + 256];
#pragma unroll
        for (int mi = 0; mi < 2; ++mi) {
#pragma unroll
            for (int reg = 0; reg < 4; ++reg) {
                int row = m0 + mi * 16 + quad * 4 + reg;
                size_t oidx = (size_t)row * HD + j;
                float hold = (float)Hhi[oidx] + (float)Hlo[oidx];
                float r = sigm(acc[mi][0 + ns][reg] + br);
                float z = sigm(acc[mi][2 + ns][reg] + bz);
                float n = tanhfast(acc[mi][4 + ns][reg] + bin + r * (acc[mi][6 + ns][reg] + bhn));
                float hnew = (1.f - z) * n + z * hold;
                _Float16 hi = (_Float16)hnew;
                Hhi[oidx] = hi;
                Hlo[oidx] = (_Float16)(hnew - (float)hi);
            }
        }
    }
}

// ---------------- pooling + head ----------------
__global__ void k_ginit(int* __restrict__ gs, int* __restrict__ ge) {
    int g = threadIdx.x;
    if (g < NG) { gs[g] = 0; ge[g] = 0; }
}

__global__ void k_bounds(const int* __restrict__ batch, int* __restrict__ gs, int* __restrict__ ge) {
    int i = blockIdx.x * 256 + threadIdx.x;
    if (i >= NN) return;
    int b = batch[i];
    if (i == 0 || batch[i - 1] != b) gs[b] = i;
    if (i == NN - 1 || batch[i + 1] != b) ge[b] = i + 1;
}

__global__ void k_pool(const _Float16* __restrict__ Hhi, const _Float16* __restrict__ Hlo,
                       const int* __restrict__ gs, const int* __restrict__ ge,
                       const float* __restrict__ Wp, const float* __restrict__ bp,
                       float* __restrict__ out) {
    __shared__ float red[HD];
    int g = blockIdx.x, tid = threadIdx.x;
    int s = gs[g], e = ge[g];
    float acc = 0.f;
    for (int n = s; n < e; ++n) {
        size_t idx = (size_t)n * HD + tid;
        acc += (float)Hhi[idx] + (float)Hlo[idx];
    }
    int cnt = e - s;
    float pooled = acc / (float)(cnt > 0 ? cnt : 1);
    red[tid] = fmaxf(pooled, 0.f) * Wp[tid];
    __syncthreads();
    for (int off = 64; off > 0; off >>= 1) {
        if (tid < off) red[tid] += red[tid + off];
        __syncthreads();
    }
    if (tid == 0) out[g] = red[0] + bp[0];
}

extern "C" void kernel_launch(void* const* d_in, const int* in_sizes, int n_in,
                              void* d_out, int out_size, void* d_ws, size_t ws_size,
                              hipStream_t stream) {
    const float* x   = (const float*)d_in[0];
    const int*   ei  = (const int*)d_in[1];
    const int*   bat = (const int*)d_in[2];
    const float* Win = (const float*)d_in[3];
    const float* Wmp = (const float*)d_in[4];
    const float* Wih = (const float*)d_in[5];
    const float* Whh = (const float*)d_in[6];
    const float* bih = (const float*)d_in[7];
    const float* bhh = (const float*)d_in[8];
    const float* Wp  = (const float*)d_in[9];
    const float* bp  = (const float*)d_in[10];
    float* out = (float*)d_out;

    const int* esrc = ei;
    const int* edst = ei + NE;

    char* w = (char*)d_ws;
    _Float16* Hhi = (_Float16*)w; w += (size_t)NN * HD * 2;
    _Float16* Hlo = (_Float16*)w; w += (size_t)NN * HD * 2;
    _Float16* Shi = (_Float16*)w; w += (size_t)NN * HD * 2;
    _Float16* Slo = (_Float16*)w; w += (size_t)NN * HD * 2;
    _Float16* Bhi = (_Float16*)w; w += (size_t)NSTEP * 512 * 256 * 2;
    _Float16* Blo = (_Float16*)w; w += (size_t)NSTEP * 512 * 256 * 2;
    int* indptr  = (int*)w;   w += 400128;            // (NN+1)*4 padded
    int* cursor  = (int*)w;   w += 400128;
    int* csr     = (int*)w;   w += (size_t)NE * 4;
    int* aux     = (int*)w;   w += 512;
    int* gs      = (int*)w;   w += NG * 4;
    int* ge      = (int*)w;   w += NG * 4;

    // CSR build
    hipMemsetAsync(cursor, 0, (size_t)NN * 4, stream);
    k_count<<<NE / 256, 256, 0, stream>>>(edst, cursor);
    k_scan1<<<NBLK, 256, 0, stream>>>(cursor, indptr, aux);
    k_scan2<<<1, 128, 0, stream>>>(aux);
    k_scan3<<<NBLK, 256, 0, stream>>>(indptr, cursor, aux);
    k_fill<<<NE / 256, 256, 0, stream>>>(esrc, edst, cursor, csr);

    // weight prep + input layer
    k_prepB<<<NSTEP * 512, 256, 0, stream>>>(Wmp, Wih, Whh, Bhi, Blo);
    k_input<<<NN / 2, 256, 0, stream>>>(x, Win, Hhi, Hlo);

    // 6 message-passing + fused GEMM/GRU steps (H updated in place)
    for (int st = 0; st < NSTEP; ++st) {
        k_agg<<<NN / 4, 256, 0, stream>>>(Hhi, Hlo, indptr, csr, Shi, Slo);
        k_ggemm<<<NN / 32, 256, 0, stream>>>(Shi, Slo, Hhi, Hlo,
                                             Bhi + (size_t)st * 512 * 256,
                                             Blo + (size_t)st * 512 * 256,
                                             bih, bhh);
    }

    // pooling + head
    k_ginit<<<1, NG, 0, stream>>>(gs, ge);
    k_bounds<<<(NN + 255) / 256, 256, 0, stream>>>(bat, gs, ge);
    k_pool<<<NG, HD, 0, stream>>>(Hhi, Hlo, gs, ge, Wp, bp, out);
}

// Round 3
// 2291.797 us; speedup vs baseline: 3.1165x; 1.3051x over previous
//
#include <hip/hip_runtime.h>

#define NN 100000
#define NE 1600000
#define NG 512
#define FIN 64
#define HD 128
#define H3 384
#define NSTEP 6
#define SCHUNK 1024
#define NBLK 98   // ceil(NN/SCHUNK)

typedef _Float16 f16x8 __attribute__((ext_vector_type(8)));
typedef _Float16 f16x4 __attribute__((ext_vector_type(4)));
typedef _Float16 f16x2 __attribute__((ext_vector_type(2)));
typedef float    f32x4 __attribute__((ext_vector_type(4)));

__device__ __forceinline__ float sigm(float x) { return 1.f / (1.f + __expf(-x)); }
__device__ __forceinline__ float tanhfast(float x) { return 2.f / (1.f + __expf(-2.f * x)) - 1.f; }

// ---------------- CSR build ----------------
__global__ void k_count(const int* __restrict__ dst, int* __restrict__ counts) {
    int e = blockIdx.x * 256 + threadIdx.x;
    if (e < NE) atomicAdd(&counts[dst[e]], 1);
}

__global__ void k_scan1(const int* __restrict__ counts, int* __restrict__ indptr, int* __restrict__ aux) {
    __shared__ int sh[256];
    int blk = blockIdx.x, tid = threadIdx.x;
    int base = blk * SCHUNK + tid * 4;
    int v0 = 0, v1 = 0, v2 = 0, v3 = 0;
    if (base + 0 < NN) v0 = counts[base + 0];
    if (base + 1 < NN) v1 = counts[base + 1];
    if (base + 2 < NN) v2 = counts[base + 2];
    if (base + 3 < NN) v3 = counts[base + 3];
    int tsum = v0 + v1 + v2 + v3;
    sh[tid] = tsum;
    __syncthreads();
    for (int off = 1; off < 256; off <<= 1) {
        int t = (tid >= off) ? sh[tid - off] : 0;
        __syncthreads();
        sh[tid] += t;
        __syncthreads();
    }
    int excl = sh[tid] - tsum;
    if (base + 0 < NN) indptr[base + 0] = excl;
    if (base + 1 < NN) indptr[base + 1] = excl + v0;
    if (base + 2 < NN) indptr[base + 2] = excl + v0 + v1;
    if (base + 3 < NN) indptr[base + 3] = excl + v0 + v1 + v2;
    if (tid == 255) aux[blk] = sh[255];
}

__global__ void k_scan2(int* __restrict__ aux) {
    __shared__ int sh[128];
    int tid = threadIdx.x;
    int v = (tid < NBLK) ? aux[tid] : 0;
    sh[tid] = v;
    __syncthreads();
    for (int off = 1; off < 128; off <<= 1) {
        int t = (tid >= off) ? sh[tid - off] : 0;
        __syncthreads();
        sh[tid] += t;
        __syncthreads();
    }
    if (tid < NBLK) aux[tid] = sh[tid] - v;   // exclusive block offsets
}

__global__ void k_scan3(int* __restrict__ indptr, int* __restrict__ cursor, const int* __restrict__ aux) {
    int blk = blockIdx.x, tid = threadIdx.x;
    int off = aux[blk];
    int base = blk * SCHUNK + tid * 4;
#pragma unroll
    for (int i = 0; i < 4; ++i) {
        int idx = base + i;
        if (idx < NN) {
            int v = indptr[idx] + off;
            indptr[idx] = v;
            cursor[idx] = v;
        }
    }
    if (blk == 0 && tid == 0) indptr[NN] = NE;
}

__global__ void k_fill(const int* __restrict__ src, const int* __restrict__ dst,
                       int* __restrict__ cursor, int* __restrict__ csr) {
    int e = blockIdx.x * 256 + threadIdx.x;
    if (e < NE) {
        int d = dst[e];
        int p = atomicAdd(&cursor[d], 1);
        csr[p] = src[e];
    }
}

// ---------------- B-matrix prep: Bcat[s][c][k] (c=0..511, k=0..255), fp16 hi/lo ----------------
// c: gate g = c>>7 (0=r_pre, 1=z_pre, 2=i_n, 3=h_n), j = c&127.
// k<128:  g!=3 ? Weff[s][k][jj]  (= dot(Wmp[s][k][:], Wih[jj][:]))  : 0
// k>=128: g!=2 ? Whh[jj][k-128] : 0
__global__ void k_prepB(const float* __restrict__ Wmp, const float* __restrict__ Wih,
                        const float* __restrict__ Whh,
                        _Float16* __restrict__ Bhi, _Float16* __restrict__ Blo) {
    __shared__ float wih[HD];
    int b = blockIdx.x;          // s*512 + c
    int s = b >> 9;
    int c = b & 511;
    int g = c >> 7;
    int j = c & 127;
    int jj = (g < 2) ? c : (j + 256);
    int k = threadIdx.x;         // 0..255
    if (k < HD) wih[k] = Wih[(size_t)jj * HD + k];
    __syncthreads();
    float val = 0.f;
    if (k < 128) {
        if (g != 3) {
            const float* wm = Wmp + ((size_t)s * HD + k) * HD;
            float acc = 0.f;
#pragma unroll 8
            for (int t = 0; t < HD; ++t) acc += wm[t] * wih[t];
            val = acc;
        }
    } else {
        if (g != 2) val = Whh[(size_t)jj * HD + (k - 128)];
    }
    _Float16 hi = (_Float16)val;
    size_t idx = (size_t)b * 256 + k;
    Bhi[idx] = hi;
    Blo[idx] = (_Float16)(val - (float)hi);
}

// ---------------- input layer: h = tanh(x @ W_in), stored fp16 hi/lo ----------------
__global__ void k_input(const float* __restrict__ x, const float* __restrict__ Win,
                        _Float16* __restrict__ Hhi, _Float16* __restrict__ Hlo) {
    __shared__ float xs[2][FIN];
    int half = threadIdx.x >> 7;
    int j = threadIdx.x & 127;
    int node = blockIdx.x * 2 + half;
    if (j < FIN) xs[half][j] = x[(size_t)node * FIN + j];
    __syncthreads();
    float acc = 0.f;
#pragma unroll 8
    for (int k = 0; k < FIN; ++k) acc += xs[half][k] * Win[(size_t)k * HD + j];
    float v = tanhfast(acc);
    _Float16 hi = (_Float16)v;
    size_t idx = (size_t)node * HD + j;
    Hhi[idx] = hi;
    Hlo[idx] = (_Float16)(v - (float)hi);
}

// ---------------- aggregation: S[v] = sum_{in-edges} (Hhi+Hlo)[src], stored fp16 hi/lo ----------------
// Wave per node: lanes 0-31 accumulate the hi array, lanes 32-63 the lo array
// (1 x 8B load per edge per lane), combined with one shfl at the end.
__global__ void k_agg(const _Float16* __restrict__ Hhi, const _Float16* __restrict__ Hlo,
                      const int* __restrict__ indptr, const int* __restrict__ csr,
                      _Float16* __restrict__ Shi, _Float16* __restrict__ Slo) {
    int v = blockIdx.x * 4 + (threadIdx.x >> 6);
    int lane = threadIdx.x & 63;
    int half = lane >> 5;
    int cq = lane & 31;          // covers halves [cq*4, cq*4+4)
    const _Float16* src = half ? Hlo : Hhi;
    int s = indptr[v], e = indptr[v + 1];
    float a0 = 0.f, a1 = 0.f, a2 = 0.f, a3 = 0.f;
    int i = s;
    for (; i + 1 < e; i += 2) {
        int u0 = csr[i], u1 = csr[i + 1];
        f16x4 t0 = *(const f16x4*)(src + (size_t)u0 * HD + cq * 4);
        f16x4 t1 = *(const f16x4*)(src + (size_t)u1 * HD + cq * 4);
        a0 += (float)t0.x + (float)t1.x;
        a1 += (float)t0.y + (float)t1.y;
        a2 += (float)t0.z + (float)t1.z;
        a3 += (float)t0.w + (float)t1.w;
    }
    if (i < e) {
        int u0 = csr[i];
        f16x4 t0 = *(const f16x4*)(src + (size_t)u0 * HD + cq * 4);
        a0 += (float)t0.x; a1 += (float)t0.y; a2 += (float)t0.z; a3 += (float)t0.w;
    }
    a0 += __shfl_down(a0, 32);
    a1 += __shfl_down(a1, 32);
    a2 += __shfl_down(a2, 32);
    a3 += __shfl_down(a3, 32);
    if (lane < 32) {
        f16x4 oh, ol;
        oh.x = (_Float16)a0; ol.x = (_Float16)(a0 - (float)oh.x);
        oh.y = (_Float16)a1; ol.y = (_Float16)(a1 - (float)oh.y);
        oh.z = (_Float16)a2; ol.z = (_Float16)(a2 - (float)oh.z);
        oh.w = (_Float16)a3; ol.w = (_Float16)(a3 - (float)oh.w);
        size_t idx = (size_t)v * HD + cq * 4;
        *(f16x4*)(Shi + idx) = oh;
        *(f16x4*)(Slo + idx) = ol;
    }
}

// ---------------- fused MFMA GEMM + GRU gates, LDS-staged B, K-phased ----------------
// Block: 64 rows x all 512 gate-cols. 4 waves split cols: wave w -> j in [w*32,w*32+32),
// 8 col-subtiles (4 gates x 2). K split into 8 phases of 32; per phase the 64KB B-slice
// (hi+lo) is staged to LDS with an XOR swizzle for bank-uniform ds_read_b128.
// H updated in place (block owns its 64 rows entirely).
__global__ void __launch_bounds__(256, 2) k_ggemm(
        const _Float16* __restrict__ Shi, const _Float16* __restrict__ Slo,
        _Float16* __restrict__ Hhi, _Float16* __restrict__ Hlo,
        const _Float16* __restrict__ Bhi, const _Float16* __restrict__ Blo,
        const float* __restrict__ bih, const float* __restrict__ bhh) {
    __shared__ _Float16 BsH[512 * 32];   // 32 KB: 512 c-rows x 32 k-halves (swizzled)
    __shared__ _Float16 BsL[512 * 32];   // 32 KB
    int tid = threadIdx.x;
    int w = tid >> 6, lane = tid & 63;
    int quad = lane >> 4, l16 = lane & 15;
    int m0 = blockIdx.x * 64;

    f32x4 acc[4][8];
#pragma unroll
    for (int mi = 0; mi < 4; ++mi)
#pragma unroll
        for (int t = 0; t < 8; ++t) acc[mi][t] = (f32x4){0.f, 0.f, 0.f, 0.f};

    size_t arow[4];
#pragma unroll
    for (int mi = 0; mi < 4; ++mi) {
        int r = m0 + mi * 16 + l16;
        arow[mi] = (size_t)(r < NN ? r : NN - 1) * HD;
    }

    int cs = tid >> 2;       // staging row within sweep
    int sub = tid & 3;       // 16B chunk within 64B slice-row

    for (int kt = 0; kt < 8; ++kt) {
        if (kt) __syncthreads();   // prior phase's LDS reads done before overwrite
        // stage B slice kt -> LDS (swizzled)
#pragma unroll
        for (int sweep = 0; sweep < 8; ++sweep) {
            int c = sweep * 64 + cs;
            size_t gsrc = (size_t)c * 256 + kt * 32 + sub * 8;
            f16x8 vh = *(const f16x8*)(Bhi + gsrc);
            f16x8 vl = *(const f16x8*)(Blo + gsrc);
            int dst = c * 32 + ((sub ^ (c & 3)) * 8);
            *(f16x8*)(&BsH[dst]) = vh;
            *(f16x8*)(&BsL[dst]) = vl;
        }
        // A fragments for this phase (overlap with staging)
        const _Float16* Ah = (kt < 4) ? Shi : Hhi;
        const _Float16* Al = (kt < 4) ? Slo : Hlo;
        int ko = (kt & 3) * 32 + quad * 8;
        f16x8 ah[4], al[4];
#pragma unroll
        for (int mi = 0; mi < 4; ++mi) {
            ah[mi] = *(const f16x8*)(Ah + arow[mi] + ko);
            al[mi] = *(const f16x8*)(Al + arow[mi] + ko);
        }
        __syncthreads();
#pragma unroll
        for (int t = 0; t < 8; ++t) {
            int lc = ((t >> 1) << 7) + w * 32 + ((t & 1) << 4) + l16;
            int bidx = lc * 32 + ((quad ^ (lc & 3)) * 8);
            f16x8 bh = *(const f16x8*)(&BsH[bidx]);
            f16x8 bl = *(const f16x8*)(&BsL[bidx]);
#pragma unroll
            for (int mi = 0; mi < 4; ++mi) {
                acc[mi][t] = __builtin_amdgcn_mfma_f32_16x16x32_f16(ah[mi], bh, acc[mi][t], 0, 0, 0);
                acc[mi][t] = __builtin_amdgcn_mfma_f32_16x16x32_f16(ah[mi], bl, acc[mi][t], 0, 0, 0);
                acc[mi][t] = __builtin_amdgcn_mfma_f32_16x16x32_f16(al[mi], bh, acc[mi][t], 0, 0, 0);
            }
        }
    }

    // epilogue: gates. C/D layout: col = lane&15, row = quad*4 + reg.
#pragma unroll
    for (int ns = 0; ns < 2; ++ns) {
        int j = w * 32 + ns * 16 + l16;
        float br  = bih[j]       + bhh[j];
        float bz  = bih[j + 128] + bhh[j + 128];
        float bin = bih[j + 256];
        float bhn = bhh[j + 256];
#pragma unroll
        for (int mi = 0; mi < 4; ++mi) {
#pragma unroll
            for (int reg = 0; reg < 4; ++reg) {
                int row = m0 + mi * 16 + quad * 4 + reg;
                if (row < NN) {
                    size_t oidx = (size_t)row * HD + j;
                    float hold = (float)Hhi[oidx] + (float)Hlo[oidx];
                    float r = sigm(acc[mi][0 + ns][reg] + br);
                    float z = sigm(acc[mi][2 + ns][reg] + bz);
                    float n = tanhfast(acc[mi][4 + ns][reg] + bin + r * (acc[mi][6 + ns][reg] + bhn));
                    float hnew = (1.f - z) * n + z * hold;
                    _Float16 hi = (_Float16)hnew;
                    Hhi[oidx] = hi;
                    Hlo[oidx] = (_Float16)(hnew - (float)hi);
                }
            }
        }
    }
}

// ---------------- pooling + head ----------------
__global__ void k_ginit(int* __restrict__ gs, int* __restrict__ ge) {
    int g = threadIdx.x;
    if (g < NG) { gs[g] = 0; ge[g] = 0; }
}

__global__ void k_bounds(const int* __restrict__ batch, int* __restrict__ gs, int* __restrict__ ge) {
    int i = blockIdx.x * 256 + threadIdx.x;
    if (i >= NN) return;
    int b = batch[i];
    if (i == 0 || batch[i - 1] != b) gs[b] = i;
    if (i == NN - 1 || batch[i + 1] != b) ge[b] = i + 1;
}

__global__ void k_pool(const _Float16* __restrict__ Hhi, const _Float16* __restrict__ Hlo,
                       const int* __restrict__ gs, const int* __restrict__ ge,
                       const float* __restrict__ Wp, const float* __restrict__ bp,
                       float* __restrict__ out) {
    __shared__ float red[HD];
    int g = blockIdx.x, tid = threadIdx.x;
    int s = gs[g], e = ge[g];
    float acc = 0.f;
    for (int n = s; n < e; ++n) {
        size_t idx = (size_t)n * HD + tid;
        acc += (float)Hhi[idx] + (float)Hlo[idx];
    }
    int cnt = e - s;
    float pooled = acc / (float)(cnt > 0 ? cnt : 1);
    red[tid] = fmaxf(pooled, 0.f) * Wp[tid];
    __syncthreads();
    for (int off = 64; off > 0; off >>= 1) {
        if (tid < off) red[tid] += red[tid + off];
        __syncthreads();
    }
    if (tid == 0) out[g] = red[0] + bp[0];
}

extern "C" void kernel_launch(void* const* d_in, const int* in_sizes, int n_in,
                              void* d_out, int out_size, void* d_ws, size_t ws_size,
                              hipStream_t stream) {
    const float* x   = (const float*)d_in[0];
    const int*   ei  = (const int*)d_in[1];
    const int*   bat = (const int*)d_in[2];
    const float* Win = (const float*)d_in[3];
    const float* Wmp = (const float*)d_in[4];
    const float* Wih = (const float*)d_in[5];
    const float* Whh = (const float*)d_in[6];
    const float* bih = (const float*)d_in[7];
    const float* bhh = (const float*)d_in[8];
    const float* Wp  = (const float*)d_in[9];
    const float* bp  = (const float*)d_in[10];
    float* out = (float*)d_out;

    const int* esrc = ei;
    const int* edst = ei + NE;

    char* w = (char*)d_ws;
    _Float16* Hhi = (_Float16*)w; w += (size_t)NN * HD * 2;
    _Float16* Hlo = (_Float16*)w; w += (size_t)NN * HD * 2;
    _Float16* Shi = (_Float16*)w; w += (size_t)NN * HD * 2;
    _Float16* Slo = (_Float16*)w; w += (size_t)NN * HD * 2;
    _Float16* Bhi = (_Float16*)w; w += (size_t)NSTEP * 512 * 256 * 2;
    _Float16* Blo = (_Float16*)w; w += (size_t)NSTEP * 512 * 256 * 2;
    int* indptr  = (int*)w;   w += 400128;            // (NN+1)*4 padded
    int* cursor  = (int*)w;   w += 400128;
    int* csr     = (int*)w;   w += (size_t)NE * 4;
    int* aux     = (int*)w;   w += 512;
    int* gs      = (int*)w;   w += NG * 4;
    int* ge      = (int*)w;   w += NG * 4;

    // CSR build
    hipMemsetAsync(cursor, 0, (size_t)NN * 4, stream);
    k_count<<<NE / 256, 256, 0, stream>>>(edst, cursor);
    k_scan1<<<NBLK, 256, 0, stream>>>(cursor, indptr, aux);
    k_scan2<<<1, 128, 0, stream>>>(aux);
    k_scan3<<<NBLK, 256, 0, stream>>>(indptr, cursor, aux);
    k_fill<<<NE / 256, 256, 0, stream>>>(esrc, edst, cursor, csr);

    // weight prep + input layer
    k_prepB<<<NSTEP * 512, 256, 0, stream>>>(Wmp, Wih, Whh, Bhi, Blo);
    k_input<<<NN / 2, 256, 0, stream>>>(x, Win, Hhi, Hlo);

    // 6 message-passing + fused GEMM/GRU steps (H updated in place)
    for (int st = 0; st < NSTEP; ++st) {
        k_agg<<<NN / 4, 256, 0, stream>>>(Hhi, Hlo, indptr, csr, Shi, Slo);
        k_ggemm<<<(NN + 63) / 64, 256, 0, stream>>>(Shi, Slo, Hhi, Hlo,
                                                    Bhi + (size_t)st * 512 * 256,
                                                    Blo + (size_t)st * 512 * 256,
                                                    bih, bhh);
    }

    // pooling + head
    k_ginit<<<1, NG, 0, stream>>>(gs, ge);
    k_bounds<<<(NN + 255) / 256, 256, 0, stream>>>(bat, gs, ge);
    k_pool<<<NG, HD, 0, stream>>>(Hhi, Hlo, gs, ge, Wp, bp, out);
}

// Round 4
// 1573.671 us; speedup vs baseline: 4.5386x; 1.4563x over previous
//
#include <hip/hip_runtime.h>

#define NN 100000
#define NE 1600000
#define NG 512
#define FIN 64
#define HD 128
#define H3 384
#define NSTEP 6
#define SCHUNK 1024
#define NBLK 98   // ceil(NN/SCHUNK)

typedef _Float16 f16x8 __attribute__((ext_vector_type(8)));
typedef _Float16 f16x4 __attribute__((ext_vector_type(4)));
typedef float    f32x4 __attribute__((ext_vector_type(4)));

__device__ __forceinline__ float sigm(float x) { return 1.f / (1.f + __expf(-x)); }
__device__ __forceinline__ float tanhfast(float x) { return 2.f / (1.f + __expf(-2.f * x)) - 1.f; }

// ---------------- CSR build ----------------
__global__ void k_count(const int* __restrict__ dst, int* __restrict__ counts) {
    int e = blockIdx.x * 256 + threadIdx.x;
    if (e < NE) atomicAdd(&counts[dst[e]], 1);
}

__global__ void k_scan1(const int* __restrict__ counts, int* __restrict__ indptr, int* __restrict__ aux) {
    __shared__ int sh[256];
    int blk = blockIdx.x, tid = threadIdx.x;
    int base = blk * SCHUNK + tid * 4;
    int v0 = 0, v1 = 0, v2 = 0, v3 = 0;
    if (base + 0 < NN) v0 = counts[base + 0];
    if (base + 1 < NN) v1 = counts[base + 1];
    if (base + 2 < NN) v2 = counts[base + 2];
    if (base + 3 < NN) v3 = counts[base + 3];
    int tsum = v0 + v1 + v2 + v3;
    sh[tid] = tsum;
    __syncthreads();
    for (int off = 1; off < 256; off <<= 1) {
        int t = (tid >= off) ? sh[tid - off] : 0;
        __syncthreads();
        sh[tid] += t;
        __syncthreads();
    }
    int excl = sh[tid] - tsum;
    if (base + 0 < NN) indptr[base + 0] = excl;
    if (base + 1 < NN) indptr[base + 1] = excl + v0;
    if (base + 2 < NN) indptr[base + 2] = excl + v0 + v1;
    if (base + 3 < NN) indptr[base + 3] = excl + v0 + v1 + v2;
    if (tid == 255) aux[blk] = sh[255];
}

__global__ void k_scan2(int* __restrict__ aux) {
    __shared__ int sh[128];
    int tid = threadIdx.x;
    int v = (tid < NBLK) ? aux[tid] : 0;
    sh[tid] = v;
    __syncthreads();
    for (int off = 1; off < 128; off <<= 1) {
        int t = (tid >= off) ? sh[tid - off] : 0;
        __syncthreads();
        sh[tid] += t;
        __syncthreads();
    }
    if (tid < NBLK) aux[tid] = sh[tid] - v;   // exclusive block offsets
}

__global__ void k_scan3(int* __restrict__ indptr, int* __restrict__ cursor, const int* __restrict__ aux) {
    int blk = blockIdx.x, tid = threadIdx.x;
    int off = aux[blk];
    int base = blk * SCHUNK + tid * 4;
#pragma unroll
    for (int i = 0; i < 4; ++i) {
        int idx = base + i;
        if (idx < NN) {
            int v = indptr[idx] + off;
            indptr[idx] = v;
            cursor[idx] = v;
        }
    }
    if (blk == 0 && tid == 0) indptr[NN] = NE;
}

__global__ void k_fill(const int* __restrict__ src, const int* __restrict__ dst,
                       int* __restrict__ cursor, int* __restrict__ csr) {
    int e = blockIdx.x * 256 + threadIdx.x;
    if (e < NE) {
        int d = dst[e];
        int p = atomicAdd(&cursor[d], 1);
        csr[p] = src[e];
    }
}

// ---------------- B-matrix prep: Bcat[s][c][k] (c=0..511, k=0..255), fp16 ----------------
// c: gate g = c>>7 (0=r, 1=z, 2=i_n, 3=h_n), j = c&127.
// k<128:  g!=3 ? Weff[s][k][jj] : 0   (Weff = Wmp[s] @ Wih^T)
// k>=128: g!=2 ? Whh[jj][k-128] : 0
__global__ void k_prepB(const float* __restrict__ Wmp, const float* __restrict__ Wih,
                        const float* __restrict__ Whh, _Float16* __restrict__ B16) {
    __shared__ float wih[HD];
    int b = blockIdx.x;          // s*512 + c
    int s = b >> 9;
    int c = b & 511;
    int g = c >> 7;
    int j = c & 127;
    int jj = (g < 2) ? c : (j + 256);
    int k = threadIdx.x;         // 0..255
    if (k < HD) wih[k] = Wih[(size_t)jj * HD + k];
    __syncthreads();
    float val = 0.f;
    if (k < 128) {
        if (g != 3) {
            const float* wm = Wmp + ((size_t)s * HD + k) * HD;
            float acc = 0.f;
#pragma unroll 8
            for (int t = 0; t < HD; ++t) acc += wm[t] * wih[t];
            val = acc;
        }
    } else {
        if (g != 2) val = Whh[(size_t)jj * HD + (k - 128)];
    }
    B16[(size_t)b * 256 + k] = (_Float16)val;
}

// ---------------- input layer: h = tanh(x @ W_in), stored fp16 hi/lo ----------------
__global__ void k_input(const float* __restrict__ x, const float* __restrict__ Win,
                        _Float16* __restrict__ Hhi, _Float16* __restrict__ Hlo) {
    __shared__ float xs[2][FIN];
    int half = threadIdx.x >> 7;
    int j = threadIdx.x & 127;
    int node = blockIdx.x * 2 + half;
    if (j < FIN) xs[half][j] = x[(size_t)node * FIN + j];
    __syncthreads();
    float acc = 0.f;
#pragma unroll 8
    for (int k = 0; k < FIN; ++k) acc += xs[half][k] * Win[(size_t)k * HD + j];
    float v = tanhfast(acc);
    _Float16 hi = (_Float16)v;
    size_t idx = (size_t)node * HD + j;
    Hhi[idx] = hi;
    Hlo[idx] = (_Float16)(v - (float)hi);
}

// ---------------- aggregation: S[v] = sum_{in-edges} Hhi[src], fp16 out ----------------
// Wave per node. Lanes split edge-parity (eh) x col-quarter (cq): 4-edge unroll per half
// -> 4 independent 8B loads in flight per lane. Combine halves with one shfl.
__global__ void k_agg(const _Float16* __restrict__ Hhi, const int* __restrict__ indptr,
                      const int* __restrict__ csr, _Float16* __restrict__ Shi) {
    int v = blockIdx.x * 4 + (threadIdx.x >> 6);
    int lane = threadIdx.x & 63;
    int eh = lane >> 5;          // edge parity for this half-wave
    int cq = lane & 31;          // cols [cq*4, cq*4+4)
    int s = indptr[v], e = indptr[v + 1];
    float a0 = 0.f, a1 = 0.f, a2 = 0.f, a3 = 0.f;
    int i = s + eh;
    for (; i + 6 < e; i += 8) {
        int u0 = csr[i], u1 = csr[i + 2], u2 = csr[i + 4], u3 = csr[i + 6];
        f16x4 t0 = *(const f16x4*)(Hhi + (size_t)u0 * HD + cq * 4);
        f16x4 t1 = *(const f16x4*)(Hhi + (size_t)u1 * HD + cq * 4);
        f16x4 t2 = *(const f16x4*)(Hhi + (size_t)u2 * HD + cq * 4);
        f16x4 t3 = *(const f16x4*)(Hhi + (size_t)u3 * HD + cq * 4);
        a0 += (float)t0.x + (float)t1.x + (float)t2.x + (float)t3.x;
        a1 += (float)t0.y + (float)t1.y + (float)t2.y + (float)t3.y;
        a2 += (float)t0.z + (float)t1.z + (float)t2.z + (float)t3.z;
        a3 += (float)t0.w + (float)t1.w + (float)t2.w + (float)t3.w;
    }
    for (; i < e; i += 2) {
        int u0 = csr[i];
        f16x4 t0 = *(const f16x4*)(Hhi + (size_t)u0 * HD + cq * 4);
        a0 += (float)t0.x; a1 += (float)t0.y; a2 += (float)t0.z; a3 += (float)t0.w;
    }
    a0 += __shfl_down(a0, 32);
    a1 += __shfl_down(a1, 32);
    a2 += __shfl_down(a2, 32);
    a3 += __shfl_down(a3, 32);
    if (lane < 32) {
        f16x4 o;
        o.x = (_Float16)a0; o.y = (_Float16)a1; o.z = (_Float16)a2; o.w = (_Float16)a3;
        *(f16x4*)(Shi + (size_t)v * HD + cq * 4) = o;
    }
}

// ---------------- fused MFMA GEMM + GRU gates, barrier-free, B direct from L2 ----------------
// Block: 32 rows x all 512 gate-cols, 4 waves split cols (wave w: j in [w*32,w*32+32),
// 8 col-subtiles t: gate g=t>>1, sub n=t&1). K: phases 0-3 read S (1-product fp16),
// phases 4-7 read H hi/lo (2-product). Structurally-zero B subtiles skipped:
// S-phases use t=0..5 (r,z,i_n); H-phases use t={0,1,2,3,6,7} (r,z,h_n).
// B (256 KB) is L2-resident; fragments read directly to VGPRs. One barrier total.
__global__ void __launch_bounds__(256, 2) k_ggemm(
        const _Float16* __restrict__ Shi,
        _Float16* __restrict__ Hhi, _Float16* __restrict__ Hlo,
        const _Float16* __restrict__ B16,
        const float* __restrict__ bih, const float* __restrict__ bhh) {
    int tid = threadIdx.x;
    int w = tid >> 6, lane = tid & 63;
    int quad = lane >> 4, l16 = lane & 15;
    int m0 = blockIdx.x * 32;

    f32x4 acc[2][8];
#pragma unroll
    for (int mi = 0; mi < 2; ++mi)
#pragma unroll
        for (int t = 0; t < 8; ++t) acc[mi][t] = (f32x4){0.f, 0.f, 0.f, 0.f};

    size_t arow0 = (size_t)(m0 + l16) * HD;
    size_t arow1 = (size_t)(m0 + 16 + l16) * HD;

    const _Float16* bptr[8];
#pragma unroll
    for (int t = 0; t < 8; ++t) {
        int c = ((t >> 1) << 7) + w * 32 + ((t & 1) << 4) + l16;
        bptr[t] = B16 + (size_t)c * 256;
    }

    // Phases 0-3: A = S (fp16, 1 product); gates r,z,i_n (t=0..5)
#pragma unroll
    for (int p = 0; p < 4; ++p) {
        int ko = p * 32 + quad * 8;
        f16x8 a0 = *(const f16x8*)(Shi + arow0 + ko);
        f16x8 a1 = *(const f16x8*)(Shi + arow1 + ko);
#pragma unroll
        for (int t = 0; t < 6; ++t) {
            f16x8 b = *(const f16x8*)(bptr[t] + ko);
            acc[0][t] = __builtin_amdgcn_mfma_f32_16x16x32_f16(a0, b, acc[0][t], 0, 0, 0);
            acc[1][t] = __builtin_amdgcn_mfma_f32_16x16x32_f16(a1, b, acc[1][t], 0, 0, 0);
        }
    }

    // Phases 4-7: A = H (hi/lo, 2 products); gates r,z,h_n (t={0,1,2,3,6,7})
#pragma unroll
    for (int p = 0; p < 4; ++p) {
        int ko = p * 32 + quad * 8;
        f16x8 ah0 = *(const f16x8*)(Hhi + arow0 + ko);
        f16x8 ah1 = *(const f16x8*)(Hhi + arow1 + ko);
        f16x8 al0 = *(const f16x8*)(Hlo + arow0 + ko);
        f16x8 al1 = *(const f16x8*)(Hlo + arow1 + ko);
#pragma unroll
        for (int tt = 0; tt < 6; ++tt) {
            int t = (tt < 4) ? tt : (tt + 2);   // 0,1,2,3,6,7
            f16x8 b = *(const f16x8*)(bptr[t] + 128 + ko);
            acc[0][t] = __builtin_amdgcn_mfma_f32_16x16x32_f16(ah0, b, acc[0][t], 0, 0, 0);
            acc[0][t] = __builtin_amdgcn_mfma_f32_16x16x32_f16(al0, b, acc[0][t], 0, 0, 0);
            acc[1][t] = __builtin_amdgcn_mfma_f32_16x16x32_f16(ah1, b, acc[1][t], 0, 0, 0);
            acc[1][t] = __builtin_amdgcn_mfma_f32_16x16x32_f16(al1, b, acc[1][t], 0, 0, 0);
        }
    }

    // All waves read the block's full H rows as A above; epilogue writes them.
    __syncthreads();

    // epilogue: gates. C/D layout: col = lane&15, row = quad*4 + reg.
    // t pairs: r=acc[.][0/1], z=acc[.][2/3], i_n=acc[.][4/5], h_n=acc[.][6/7].
#pragma unroll
    for (int ns = 0; ns < 2; ++ns) {
        int j = w * 32 + ns * 16 + l16;
        float br  = bih[j]       + bhh[j];
        float bz  = bih[j + 128] + bhh[j + 128];
        float bin = bih[j + 256];
        float bhn = bhh[j + 256];
#pragma unroll
        for (int mi = 0; mi < 2; ++mi) {
#pragma unroll
            for (int reg = 0; reg < 4; ++reg) {
                int row = m0 + mi * 16 + quad * 4 + reg;
                size_t oidx = (size_t)row * HD + j;
                float hold = (float)Hhi[oidx] + (float)Hlo[oidx];
                float r = sigm(acc[mi][0 + ns][reg] + br);
                float z = sigm(acc[mi][2 + ns][reg] + bz);
                float n = tanhfast(acc[mi][4 + ns][reg] + bin + r * (acc[mi][6 + ns][reg] + bhn));
                float hnew = (1.f - z) * n + z * hold;
                _Float16 hi = (_Float16)hnew;
                Hhi[oidx] = hi;
                Hlo[oidx] = (_Float16)(hnew - (float)hi);
            }
        }
    }
}

// ---------------- pooling + head ----------------
__global__ void k_ginit(int* __restrict__ gs, int* __restrict__ ge) {
    int g = threadIdx.x;
    if (g < NG) { gs[g] = 0; ge[g] = 0; }
}

__global__ void k_bounds(const int* __restrict__ batch, int* __restrict__ gs, int* __restrict__ ge) {
    int i = blockIdx.x * 256 + threadIdx.x;
    if (i >= NN) return;
    int b = batch[i];
    if (i == 0 || batch[i - 1] != b) gs[b] = i;
    if (i == NN - 1 || batch[i + 1] != b) ge[b] = i + 1;
}

__global__ void k_pool(const _Float16* __restrict__ Hhi, const _Float16* __restrict__ Hlo,
                       const int* __restrict__ gs, const int* __restrict__ ge,
                       const float* __restrict__ Wp, const float* __restrict__ bp,
                       float* __restrict__ out) {
    __shared__ float red[HD];
    int g = blockIdx.x, tid = threadIdx.x;
    int s = gs[g], e = ge[g];
    float acc = 0.f;
    for (int n = s; n < e; ++n) {
        size_t idx = (size_t)n * HD + tid;
        acc += (float)Hhi[idx] + (float)Hlo[idx];
    }
    int cnt = e - s;
    float pooled = acc / (float)(cnt > 0 ? cnt : 1);
    red[tid] = fmaxf(pooled, 0.f) * Wp[tid];
    __syncthreads();
    for (int off = 64; off > 0; off >>= 1) {
        if (tid < off) red[tid] += red[tid + off];
        __syncthreads();
    }
    if (tid == 0) out[g] = red[0] + bp[0];
}

extern "C" void kernel_launch(void* const* d_in, const int* in_sizes, int n_in,
                              void* d_out, int out_size, void* d_ws, size_t ws_size,
                              hipStream_t stream) {
    const float* x   = (const float*)d_in[0];
    const int*   ei  = (const int*)d_in[1];
    const int*   bat = (const int*)d_in[2];
    const float* Win = (const float*)d_in[3];
    const float* Wmp = (const float*)d_in[4];
    const float* Wih = (const float*)d_in[5];
    const float* Whh = (const float*)d_in[6];
    const float* bih = (const float*)d_in[7];
    const float* bhh = (const float*)d_in[8];
    const float* Wp  = (const float*)d_in[9];
    const float* bp  = (const float*)d_in[10];
    float* out = (float*)d_out;

    const int* esrc = ei;
    const int* edst = ei + NE;

    char* w = (char*)d_ws;
    _Float16* Hhi = (_Float16*)w; w += (size_t)NN * HD * 2;
    _Float16* Hlo = (_Float16*)w; w += (size_t)NN * HD * 2;
    _Float16* Shi = (_Float16*)w; w += (size_t)NN * HD * 2;
    _Float16* B16 = (_Float16*)w; w += (size_t)NSTEP * 512 * 256 * 2;
    int* indptr  = (int*)w;   w += 400128;            // (NN+1)*4 padded
    int* cursor  = (int*)w;   w += 400128;
    int* csr     = (int*)w;   w += (size_t)NE * 4;
    int* aux     = (int*)w;   w += 512;
    int* gs      = (int*)w;   w += NG * 4;
    int* ge      = (int*)w;   w += NG * 4;

    // CSR build
    hipMemsetAsync(cursor, 0, (size_t)NN * 4, stream);
    k_count<<<NE / 256, 256, 0, stream>>>(edst, cursor);
    k_scan1<<<NBLK, 256, 0, stream>>>(cursor, indptr, aux);
    k_scan2<<<1, 128, 0, stream>>>(aux);
    k_scan3<<<NBLK, 256, 0, stream>>>(indptr, cursor, aux);
    k_fill<<<NE / 256, 256, 0, stream>>>(esrc, edst, cursor, csr);

    // weight prep + input layer
    k_prepB<<<NSTEP * 512, 256, 0, stream>>>(Wmp, Wih, Whh, B16);
    k_input<<<NN / 2, 256, 0, stream>>>(x, Win, Hhi, Hlo);

    // 6 message-passing + fused GEMM/GRU steps (H updated in place)
    for (int st = 0; st < NSTEP; ++st) {
        k_agg<<<NN / 4, 256, 0, stream>>>(Hhi, indptr, csr, Shi);
        k_ggemm<<<NN / 32, 256, 0, stream>>>(Shi, Hhi, Hlo,
                                             B16 + (size_t)st * 512 * 256,
                                             bih, bhh);
    }

    // pooling + head
    k_ginit<<<1, NG, 0, stream>>>(gs, ge);
    k_bounds<<<(NN + 255) / 256, 256, 0, stream>>>(bat, gs, ge);
    k_pool<<<NG, HD, 0, stream>>>(Hhi, Hlo, gs, ge, Wp, bp, out);
}

// Round 5
// 1566.131 us; speedup vs baseline: 4.5605x; 1.0048x over previous
//
#include <hip/hip_runtime.h>

#define NN 100000
#define NE 1600000
#define NG 512
#define FIN 64
#define HD 128
#define H3 384
#define NSTEP 6
#define SCHUNK 1024
#define NBLK 98   // ceil(NN/SCHUNK)

typedef _Float16 f16x8 __attribute__((ext_vector_type(8)));
typedef _Float16 f16x4 __attribute__((ext_vector_type(4)));
typedef float    f32x4 __attribute__((ext_vector_type(4)));

__device__ __forceinline__ float sigm(float x) { return 1.f / (1.f + __expf(-x)); }
__device__ __forceinline__ float tanhfast(float x) { return 2.f / (1.f + __expf(-2.f * x)) - 1.f; }

// ---------------- CSR build ----------------
__global__ void k_count(const int* __restrict__ dst, int* __restrict__ counts) {
    int e = blockIdx.x * 256 + threadIdx.x;
    if (e < NE) atomicAdd(&counts[dst[e]], 1);
}

__global__ void k_scan1(const int* __restrict__ counts, int* __restrict__ indptr, int* __restrict__ aux) {
    __shared__ int sh[256];
    int blk = blockIdx.x, tid = threadIdx.x;
    int base = blk * SCHUNK + tid * 4;
    int v0 = 0, v1 = 0, v2 = 0, v3 = 0;
    if (base + 0 < NN) v0 = counts[base + 0];
    if (base + 1 < NN) v1 = counts[base + 1];
    if (base + 2 < NN) v2 = counts[base + 2];
    if (base + 3 < NN) v3 = counts[base + 3];
    int tsum = v0 + v1 + v2 + v3;
    sh[tid] = tsum;
    __syncthreads();
    for (int off = 1; off < 256; off <<= 1) {
        int t = (tid >= off) ? sh[tid - off] : 0;
        __syncthreads();
        sh[tid] += t;
        __syncthreads();
    }
    int excl = sh[tid] - tsum;
    if (base + 0 < NN) indptr[base + 0] = excl;
    if (base + 1 < NN) indptr[base + 1] = excl + v0;
    if (base + 2 < NN) indptr[base + 2] = excl + v0 + v1;
    if (base + 3 < NN) indptr[base + 3] = excl + v0 + v1 + v2;
    if (tid == 255) aux[blk] = sh[255];
}

__global__ void k_scan2(int* __restrict__ aux) {
    __shared__ int sh[128];
    int tid = threadIdx.x;
    int v = (tid < NBLK) ? aux[tid] : 0;
    sh[tid] = v;
    __syncthreads();
    for (int off = 1; off < 128; off <<= 1) {
        int t = (tid >= off) ? sh[tid - off] : 0;
        __syncthreads();
        sh[tid] += t;
        __syncthreads();
    }
    if (tid < NBLK) aux[tid] = sh[tid] - v;   // exclusive block offsets
}

__global__ void k_scan3(int* __restrict__ indptr, int* __restrict__ cursor, const int* __restrict__ aux) {
    int blk = blockIdx.x, tid = threadIdx.x;
    int off = aux[blk];
    int base = blk * SCHUNK + tid * 4;
#pragma unroll
    for (int i = 0; i < 4; ++i) {
        int idx = base + i;
        if (idx < NN) {
            int v = indptr[idx] + off;
            indptr[idx] = v;
            cursor[idx] = v;
        }
    }
    if (blk == 0 && tid == 0) indptr[NN] = NE;
}

__global__ void k_fill(const int* __restrict__ src, const int* __restrict__ dst,
                       int* __restrict__ cursor, int* __restrict__ csr) {
    int e = blockIdx.x * 256 + threadIdx.x;
    if (e < NE) {
        int d = dst[e];
        int p = atomicAdd(&cursor[d], 1);
        csr[p] = src[e];
    }
}

// ---------------- B-matrix prep: Bcat[s][c][k] (c=0..511, k=0..255), fp16 ----------------
__global__ void k_prepB(const float* __restrict__ Wmp, const float* __restrict__ Wih,
                        const float* __restrict__ Whh, _Float16* __restrict__ B16) {
    __shared__ float wih[HD];
    int b = blockIdx.x;          // s*512 + c
    int s = b >> 9;
    int c = b & 511;
    int g = c >> 7;
    int j = c & 127;
    int jj = (g < 2) ? c : (j + 256);
    int k = threadIdx.x;         // 0..255
    if (k < HD) wih[k] = Wih[(size_t)jj * HD + k];
    __syncthreads();
    float val = 0.f;
    if (k < 128) {
        if (g != 3) {
            const float* wm = Wmp + ((size_t)s * HD + k) * HD;
            float acc = 0.f;
#pragma unroll 8
            for (int t = 0; t < HD; ++t) acc += wm[t] * wih[t];
            val = acc;
        }
    } else {
        if (g != 2) val = Whh[(size_t)jj * HD + (k - 128)];
    }
    B16[(size_t)b * 256 + k] = (_Float16)val;
}

// ---------------- input layer: h = tanh(x @ W_in), stored fp16 hi/lo ----------------
__global__ void k_input(const float* __restrict__ x, const float* __restrict__ Win,
                        _Float16* __restrict__ Hhi, _Float16* __restrict__ Hlo) {
    __shared__ float xs[2][FIN];
    int half = threadIdx.x >> 7;
    int j = threadIdx.x & 127;
    int node = blockIdx.x * 2 + half;
    if (j < FIN) xs[half][j] = x[(size_t)node * FIN + j];
    __syncthreads();
    float acc = 0.f;
#pragma unroll 8
    for (int k = 0; k < FIN; ++k) acc += xs[half][k] * Win[(size_t)k * HD + j];
    float v = tanhfast(acc);
    _Float16 hi = (_Float16)v;
    size_t idx = (size_t)node * HD + j;
    Hhi[idx] = hi;
    Hlo[idx] = (_Float16)(v - (float)hi);
}

// ---------------- aggregation: S[v] = sum_{in-edges} Hhi[src], fp16 out ----------------
// Wave per node. lane = edge-slot (lane>>4, 4 slots) x col-group (lane&15, 8 cols, 16B loads).
// 2 independent 16B loads in flight per lane; 2-level shfl reduction.
__global__ void k_agg(const _Float16* __restrict__ Hhi, const int* __restrict__ indptr,
                      const int* __restrict__ csr, _Float16* __restrict__ Shi) {
    int v = blockIdx.x * 4 + (threadIdx.x >> 6);
    int lane = threadIdx.x & 63;
    int slot = lane >> 4;        // edge slot 0..3
    int cg = lane & 15;          // cols [cg*8, cg*8+8)
    int s = indptr[v], e = indptr[v + 1];
    float a0 = 0.f, a1 = 0.f, a2 = 0.f, a3 = 0.f, a4 = 0.f, a5 = 0.f, a6 = 0.f, a7 = 0.f;
    int i = s + slot;
    for (; i + 4 < e; i += 8) {
        int u0 = csr[i], u1 = csr[i + 4];
        f16x8 t0 = *(const f16x8*)(Hhi + (size_t)u0 * HD + cg * 8);
        f16x8 t1 = *(const f16x8*)(Hhi + (size_t)u1 * HD + cg * 8);
        a0 += (float)t0[0] + (float)t1[0];
        a1 += (float)t0[1] + (float)t1[1];
        a2 += (float)t0[2] + (float)t1[2];
        a3 += (float)t0[3] + (float)t1[3];
        a4 += (float)t0[4] + (float)t1[4];
        a5 += (float)t0[5] + (float)t1[5];
        a6 += (float)t0[6] + (float)t1[6];
        a7 += (float)t0[7] + (float)t1[7];
    }
    if (i < e) {
        int u0 = csr[i];
        f16x8 t0 = *(const f16x8*)(Hhi + (size_t)u0 * HD + cg * 8);
        a0 += (float)t0[0]; a1 += (float)t0[1]; a2 += (float)t0[2]; a3 += (float)t0[3];
        a4 += (float)t0[4]; a5 += (float)t0[5]; a6 += (float)t0[6]; a7 += (float)t0[7];
    }
    a0 += __shfl_down(a0, 32); a1 += __shfl_down(a1, 32);
    a2 += __shfl_down(a2, 32); a3 += __shfl_down(a3, 32);
    a4 += __shfl_down(a4, 32); a5 += __shfl_down(a5, 32);
    a6 += __shfl_down(a6, 32); a7 += __shfl_down(a7, 32);
    a0 += __shfl_down(a0, 16); a1 += __shfl_down(a1, 16);
    a2 += __shfl_down(a2, 16); a3 += __shfl_down(a3, 16);
    a4 += __shfl_down(a4, 16); a5 += __shfl_down(a5, 16);
    a6 += __shfl_down(a6, 16); a7 += __shfl_down(a7, 16);
    if (lane < 16) {
        f16x8 o;
        o[0] = (_Float16)a0; o[1] = (_Float16)a1; o[2] = (_Float16)a2; o[3] = (_Float16)a3;
        o[4] = (_Float16)a4; o[5] = (_Float16)a5; o[6] = (_Float16)a6; o[7] = (_Float16)a7;
        *(f16x8*)(Shi + (size_t)v * HD + cg * 8) = o;
    }
}

// ---------------- fused MFMA GEMM + GRU gates ----------------
// Block: 64 rows x all 512 gate-cols, 4 waves split cols (wave w: j in [w*32,w*32+32)).
// K phases 0-3: A=S (1 product, gates r,z,i_n -> t=0..5).
// K phases 4-7: A=H hi/lo (2 products, gates r,z,h_n -> t={0,1,2,3,6,7}).
// hold(H) obtained via identity-B MFMA during phase p==w (no epilogue H re-read).
// One barrier (all waves' H reads done before epilogue writes). H updated in place.
__global__ void __launch_bounds__(256, 2) k_ggemm(
        const _Float16* __restrict__ Shi,
        _Float16* __restrict__ Hhi, _Float16* __restrict__ Hlo,
        const _Float16* __restrict__ B16,
        const float* __restrict__ bih, const float* __restrict__ bhh) {
    int tid = threadIdx.x;
    int w = tid >> 6, lane = tid & 63;
    int quad = lane >> 4, l16 = lane & 15;
    int m0 = blockIdx.x * 64;

    f32x4 acc[4][8];
    f32x4 hold[4][2];
#pragma unroll
    for (int mi = 0; mi < 4; ++mi) {
#pragma unroll
        for (int t = 0; t < 8; ++t) acc[mi][t] = (f32x4){0.f, 0.f, 0.f, 0.f};
        hold[mi][0] = (f32x4){0.f, 0.f, 0.f, 0.f};
        hold[mi][1] = (f32x4){0.f, 0.f, 0.f, 0.f};
    }

    size_t arow[4];
#pragma unroll
    for (int mi = 0; mi < 4; ++mi) {
        int r = m0 + mi * 16 + l16;
        arow[mi] = (size_t)(r < NN ? r : NN - 1) * HD;
    }

    const _Float16* bptr[8];
#pragma unroll
    for (int t = 0; t < 8; ++t) {
        int c = ((t >> 1) << 7) + w * 32 + ((t & 1) << 4) + l16;
        bptr[t] = B16 + (size_t)c * 256;
    }

    // Phases 0-3: A = S (fp16, 1 product); gates r,z,i_n (t=0..5)
#pragma unroll
    for (int p = 0; p < 4; ++p) {
        int ko = p * 32 + quad * 8;
        f16x8 a[4];
#pragma unroll
        for (int mi = 0; mi < 4; ++mi) a[mi] = *(const f16x8*)(Shi + arow[mi] + ko);
#pragma unroll
        for (int t = 0; t < 6; ++t) {
            f16x8 b = *(const f16x8*)(bptr[t] + ko);
#pragma unroll
            for (int mi = 0; mi < 4; ++mi)
                acc[mi][t] = __builtin_amdgcn_mfma_f32_16x16x32_f16(a[mi], b, acc[mi][t], 0, 0, 0);
        }
    }

    // identity B fragments: B[k][c] = (k == ns*16 + c)
    f16x8 bid0, bid1;
#pragma unroll
    for (int jj = 0; jj < 8; ++jj) {
        int k = quad * 8 + jj;
        bid0[jj] = (k == l16) ? (_Float16)1.0f : (_Float16)0.0f;
        bid1[jj] = (k == 16 + l16) ? (_Float16)1.0f : (_Float16)0.0f;
    }

    // Phases 4-7: A = H (hi/lo, 2 products); gates r,z,h_n (t={0,1,2,3,6,7})
#pragma unroll
    for (int p = 0; p < 4; ++p) {
        int ko = p * 32 + quad * 8;
        f16x8 ah[4], al[4];
#pragma unroll
        for (int mi = 0; mi < 4; ++mi) {
            ah[mi] = *(const f16x8*)(Hhi + arow[mi] + ko);
            al[mi] = *(const f16x8*)(Hlo + arow[mi] + ko);
        }
#pragma unroll
        for (int tt = 0; tt < 6; ++tt) {
            int t = (tt < 4) ? tt : (tt + 2);   // 0,1,2,3,6,7
            f16x8 b = *(const f16x8*)(bptr[t] + 128 + ko);
#pragma unroll
            for (int mi = 0; mi < 4; ++mi) {
                acc[mi][t] = __builtin_amdgcn_mfma_f32_16x16x32_f16(ah[mi], b, acc[mi][t], 0, 0, 0);
                acc[mi][t] = __builtin_amdgcn_mfma_f32_16x16x32_f16(al[mi], b, acc[mi][t], 0, 0, 0);
            }
        }
        if (p == w) {   // hold = H rows at cols [w*32, w*32+32) via identity-B MFMA
#pragma unroll
            for (int mi = 0; mi < 4; ++mi) {
                hold[mi][0] = __builtin_amdgcn_mfma_f32_16x16x32_f16(ah[mi], bid0, hold[mi][0], 0, 0, 0);
                hold[mi][0] = __builtin_amdgcn_mfma_f32_16x16x32_f16(al[mi], bid0, hold[mi][0], 0, 0, 0);
                hold[mi][1] = __builtin_amdgcn_mfma_f32_16x16x32_f16(ah[mi], bid1, hold[mi][1], 0, 0, 0);
                hold[mi][1] = __builtin_amdgcn_mfma_f32_16x16x32_f16(al[mi], bid1, hold[mi][1], 0, 0, 0);
            }
        }
    }

    // all waves' H reads complete before any epilogue write
    __syncthreads();

    // epilogue: gates. C/D layout: col = lane&15, row = quad*4 + reg.
#pragma unroll
    for (int ns = 0; ns < 2; ++ns) {
        int j = w * 32 + ns * 16 + l16;
        float br  = bih[j]       + bhh[j];
        float bz  = bih[j + 128] + bhh[j + 128];
        float bin = bih[j + 256];
        float bhn = bhh[j + 256];
#pragma unroll
        for (int mi = 0; mi < 4; ++mi) {
#pragma unroll
            for (int reg = 0; reg < 4; ++reg) {
                int row = m0 + mi * 16 + quad * 4 + reg;
                if (row < NN) {
                    size_t oidx = (size_t)row * HD + j;
                    float r = sigm(acc[mi][0 + ns][reg] + br);
                    float z = sigm(acc[mi][2 + ns][reg] + bz);
                    float n = tanhfast(acc[mi][4 + ns][reg] + bin + r * (acc[mi][6 + ns][reg] + bhn));
                    float hnew = (1.f - z) * n + z * hold[mi][ns][reg];
                    _Float16 hi = (_Float16)hnew;
                    Hhi[oidx] = hi;
                    Hlo[oidx] = (_Float16)(hnew - (float)hi);
                }
            }
        }
    }
}

// ---------------- pooling + head ----------------
__global__ void k_ginit(int* __restrict__ gs, int* __restrict__ ge) {
    int g = threadIdx.x;
    if (g < NG) { gs[g] = 0; ge[g] = 0; }
}

__global__ void k_bounds(const int* __restrict__ batch, int* __restrict__ gs, int* __restrict__ ge) {
    int i = blockIdx.x * 256 + threadIdx.x;
    if (i >= NN) return;
    int b = batch[i];
    if (i == 0 || batch[i - 1] != b) gs[b] = i;
    if (i == NN - 1 || batch[i + 1] != b) ge[b] = i + 1;
}

__global__ void k_pool(const _Float16* __restrict__ Hhi, const _Float16* __restrict__ Hlo,
                       const int* __restrict__ gs, const int* __restrict__ ge,
                       const float* __restrict__ Wp, const float* __restrict__ bp,
                       float* __restrict__ out) {
    __shared__ float red[HD];
    int g = blockIdx.x, tid = threadIdx.x;
    int s = gs[g], e = ge[g];
    float acc = 0.f;
    for (int n = s; n < e; ++n) {
        size_t idx = (size_t)n * HD + tid;
        acc += (float)Hhi[idx] + (float)Hlo[idx];
    }
    int cnt = e - s;
    float pooled = acc / (float)(cnt > 0 ? cnt : 1);
    red[tid] = fmaxf(pooled, 0.f) * Wp[tid];
    __syncthreads();
    for (int off = 64; off > 0; off >>= 1) {
        if (tid < off) red[tid] += red[tid + off];
        __syncthreads();
    }
    if (tid == 0) out[g] = red[0] + bp[0];
}

extern "C" void kernel_launch(void* const* d_in, const int* in_sizes, int n_in,
                              void* d_out, int out_size, void* d_ws, size_t ws_size,
                              hipStream_t stream) {
    const float* x   = (const float*)d_in[0];
    const int*   ei  = (const int*)d_in[1];
    const int*   bat = (const int*)d_in[2];
    const float* Win = (const float*)d_in[3];
    const float* Wmp = (const float*)d_in[4];
    const float* Wih = (const float*)d_in[5];
    const float* Whh = (const float*)d_in[6];
    const float* bih = (const float*)d_in[7];
    const float* bhh = (const float*)d_in[8];
    const float* Wp  = (const float*)d_in[9];
    const float* bp  = (const float*)d_in[10];
    float* out = (float*)d_out;

    const int* esrc = ei;
    const int* edst = ei + NE;

    char* w = (char*)d_ws;
    _Float16* Hhi = (_Float16*)w; w += (size_t)NN * HD * 2;
    _Float16* Hlo = (_Float16*)w; w += (size_t)NN * HD * 2;
    _Float16* Shi = (_Float16*)w; w += (size_t)NN * HD * 2;
    _Float16* B16 = (_Float16*)w; w += (size_t)NSTEP * 512 * 256 * 2;
    int* indptr  = (int*)w;   w += 400128;            // (NN+1)*4 padded
    int* cursor  = (int*)w;   w += 400128;
    int* csr     = (int*)w;   w += (size_t)NE * 4;
    int* aux     = (int*)w;   w += 512;
    int* gs      = (int*)w;   w += NG * 4;
    int* ge      = (int*)w;   w += NG * 4;

    // CSR build
    hipMemsetAsync(cursor, 0, (size_t)NN * 4, stream);
    k_count<<<NE / 256, 256, 0, stream>>>(edst, cursor);
    k_scan1<<<NBLK, 256, 0, stream>>>(cursor, indptr, aux);
    k_scan2<<<1, 128, 0, stream>>>(aux);
    k_scan3<<<NBLK, 256, 0, stream>>>(indptr, cursor, aux);
    k_fill<<<NE / 256, 256, 0, stream>>>(esrc, edst, cursor, csr);

    // weight prep + input layer
    k_prepB<<<NSTEP * 512, 256, 0, stream>>>(Wmp, Wih, Whh, B16);
    k_input<<<NN / 2, 256, 0, stream>>>(x, Win, Hhi, Hlo);

    // 6 message-passing + fused GEMM/GRU steps (H updated in place)
    for (int st = 0; st < NSTEP; ++st) {
        k_agg<<<NN / 4, 256, 0, stream>>>(Hhi, indptr, csr, Shi);
        k_ggemm<<<(NN + 63) / 64, 256, 0, stream>>>(Shi, Hhi, Hlo,
                                                    B16 + (size_t)st * 512 * 256,
                                                    bih, bhh);
    }

    // pooling + head
    k_ginit<<<1, NG, 0, stream>>>(gs, ge);
    k_bounds<<<(NN + 255) / 256, 256, 0, stream>>>(bat, gs, ge);
    k_pool<<<NG, HD, 0, stream>>>(Hhi, Hlo, gs, ge, Wp, bp, out);
}

// Round 6
// 1341.440 us; speedup vs baseline: 5.3244x; 1.1675x over previous
//
#include <hip/hip_runtime.h>

#define NN 100000
#define NE 1600000
#define NG 512
#define FIN 64
#define HD 128
#define H3 384
#define NSTEP 6
#define SCHUNK 1024
#define NBLK 98   // ceil(NN/SCHUNK)

typedef _Float16 f16x8 __attribute__((ext_vector_type(8)));
typedef _Float16 f16x4 __attribute__((ext_vector_type(4)));
typedef float    f32x4 __attribute__((ext_vector_type(4)));

__device__ __forceinline__ float sigm(float x) { return 1.f / (1.f + __expf(-x)); }
__device__ __forceinline__ float tanhfast(float x) { return 2.f / (1.f + __expf(-2.f * x)) - 1.f; }

// LDS tile index with XOR swizzle: row-local r (0..63), col 0..127 halves.
// chunk (16B) = col>>3, swizzled by row&15 -> wave-parallel ds_read_b128 is 2-way max.
__device__ __forceinline__ int lidx(int r, int col) {
    return r * 128 + ((((col >> 3) ^ (r & 15)) << 3) | (col & 7));
}

// ---------------- CSR build ----------------
__global__ void k_count(const int* __restrict__ dst, int* __restrict__ counts) {
    int e = blockIdx.x * 256 + threadIdx.x;
    if (e < NE) atomicAdd(&counts[dst[e]], 1);
}

__global__ void k_scan1(const int* __restrict__ counts, int* __restrict__ indptr, int* __restrict__ aux) {
    __shared__ int sh[256];
    int blk = blockIdx.x, tid = threadIdx.x;
    int base = blk * SCHUNK + tid * 4;
    int v0 = 0, v1 = 0, v2 = 0, v3 = 0;
    if (base + 0 < NN) v0 = counts[base + 0];
    if (base + 1 < NN) v1 = counts[base + 1];
    if (base + 2 < NN) v2 = counts[base + 2];
    if (base + 3 < NN) v3 = counts[base + 3];
    int tsum = v0 + v1 + v2 + v3;
    sh[tid] = tsum;
    __syncthreads();
    for (int off = 1; off < 256; off <<= 1) {
        int t = (tid >= off) ? sh[tid - off] : 0;
        __syncthreads();
        sh[tid] += t;
        __syncthreads();
    }
    int excl = sh[tid] - tsum;
    if (base + 0 < NN) indptr[base + 0] = excl;
    if (base + 1 < NN) indptr[base + 1] = excl + v0;
    if (base + 2 < NN) indptr[base + 2] = excl + v0 + v1;
    if (base + 3 < NN) indptr[base + 3] = excl + v0 + v1 + v2;
    if (tid == 255) aux[blk] = sh[255];
}

__global__ void k_scan2(int* __restrict__ aux) {
    __shared__ int sh[128];
    int tid = threadIdx.x;
    int v = (tid < NBLK) ? aux[tid] : 0;
    sh[tid] = v;
    __syncthreads();
    for (int off = 1; off < 128; off <<= 1) {
        int t = (tid >= off) ? sh[tid - off] : 0;
        __syncthreads();
        sh[tid] += t;
        __syncthreads();
    }
    if (tid < NBLK) aux[tid] = sh[tid] - v;   // exclusive block offsets
}

__global__ void k_scan3(int* __restrict__ indptr, int* __restrict__ cursor, const int* __restrict__ aux) {
    int blk = blockIdx.x, tid = threadIdx.x;
    int off = aux[blk];
    int base = blk * SCHUNK + tid * 4;
#pragma unroll
    for (int i = 0; i < 4; ++i) {
        int idx = base + i;
        if (idx < NN) {
            int v = indptr[idx] + off;
            indptr[idx] = v;
            cursor[idx] = v;
        }
    }
    if (blk == 0 && tid == 0) indptr[NN] = NE;
}

__global__ void k_fill(const int* __restrict__ src, const int* __restrict__ dst,
                       int* __restrict__ cursor, int* __restrict__ csr) {
    int e = blockIdx.x * 256 + threadIdx.x;
    if (e < NE) {
        int d = dst[e];
        int p = atomicAdd(&cursor[d], 1);
        csr[p] = src[e];
    }
}

// ---------------- B prep, swizzled to MFMA fragment order ----------------
// Logical Bcat[c][k]: c=0..511 (gate g=c>>7: 0=r,1=z,2=i_n,3=h_n; j=c&127), k=0..255.
//   k<128:  g!=3 ? Weff[s][k][jj] : 0    (Weff = Wmp[s] @ Wih^T)
//   k>=128: g!=2 ? Whh[jj][k-128] : 0
// Stored at Bsw[s][ ((w*8+t)*8+p)*64 + quad*16+l16 ][jj] so a wave's fragment load is
// contiguous 1KB: w=(c>>5)&3, t=(c>>7)*2+((c>>4)&1), l16=c&15, p=k>>5, quad=(k>>3)&3, jj=k&7.
__global__ void k_prepB(const float* __restrict__ Wmp, const float* __restrict__ Wih,
                        const float* __restrict__ Whh, _Float16* __restrict__ Bsw) {
    __shared__ float wih[HD];
    int b = blockIdx.x;          // s*512 + c
    int s = b >> 9;
    int c = b & 511;
    int g = c >> 7;
    int j = c & 127;
    int jj = (g < 2) ? c : (j + 256);
    int k = threadIdx.x;         // 0..255
    if (k < HD) wih[k] = Wih[(size_t)jj * HD + k];
    __syncthreads();
    float val = 0.f;
    if (k < 128) {
        if (g != 3) {
            const float* wm = Wmp + ((size_t)s * HD + k) * HD;
            float acc = 0.f;
#pragma unroll 8
            for (int t = 0; t < HD; ++t) acc += wm[t] * wih[t];
            val = acc;
        }
    } else {
        if (g != 2) val = Whh[(size_t)jj * HD + (k - 128)];
    }
    int l16 = c & 15, sub = (c >> 4) & 1, w = (c >> 5) & 3;
    int t = g * 2 + sub;
    int p = k >> 5, quad = (k >> 3) & 3, je = k & 7;
    size_t idx = (size_t)s * 131072 + ((size_t)((w * 8 + t) * 8 + p) * 64 + quad * 16 + l16) * 8 + je;
    Bsw[idx] = (_Float16)val;
}

// ---------------- input layer: h = tanh(x @ W_in), stored fp16 hi/lo ----------------
__global__ void k_input(const float* __restrict__ x, const float* __restrict__ Win,
                        _Float16* __restrict__ Hhi, _Float16* __restrict__ Hlo) {
    __shared__ float xs[2][FIN];
    int half = threadIdx.x >> 7;
    int j = threadIdx.x & 127;
    int node = blockIdx.x * 2 + half;
    if (j < FIN) xs[half][j] = x[(size_t)node * FIN + j];
    __syncthreads();
    float acc = 0.f;
#pragma unroll 8
    for (int k = 0; k < FIN; ++k) acc += xs[half][k] * Win[(size_t)k * HD + j];
    float v = tanhfast(acc);
    _Float16 hi = (_Float16)v;
    size_t idx = (size_t)node * HD + j;
    Hhi[idx] = hi;
    Hlo[idx] = (_Float16)(v - (float)hi);
}

// ---------------- aggregation: S[v] = sum_{in-edges} Hhi[src], fp16 out ----------------
__global__ void k_agg(const _Float16* __restrict__ Hhi, const int* __restrict__ indptr,
                      const int* __restrict__ csr, _Float16* __restrict__ Shi) {
    int v = blockIdx.x * 4 + (threadIdx.x >> 6);
    int lane = threadIdx.x & 63;
    int slot = lane >> 4;        // edge slot 0..3
    int cg = lane & 15;          // cols [cg*8, cg*8+8)
    int s = indptr[v], e = indptr[v + 1];
    float a0 = 0.f, a1 = 0.f, a2 = 0.f, a3 = 0.f, a4 = 0.f, a5 = 0.f, a6 = 0.f, a7 = 0.f;
    int i = s + slot;
    for (; i + 4 < e; i += 8) {
        int u0 = csr[i], u1 = csr[i + 4];
        f16x8 t0 = *(const f16x8*)(Hhi + (size_t)u0 * HD + cg * 8);
        f16x8 t1 = *(const f16x8*)(Hhi + (size_t)u1 * HD + cg * 8);
        a0 += (float)t0[0] + (float)t1[0];
        a1 += (float)t0[1] + (float)t1[1];
        a2 += (float)t0[2] + (float)t1[2];
        a3 += (float)t0[3] + (float)t1[3];
        a4 += (float)t0[4] + (float)t1[4];
        a5 += (float)t0[5] + (float)t1[5];
        a6 += (float)t0[6] + (float)t1[6];
        a7 += (float)t0[7] + (float)t1[7];
    }
    if (i < e) {
        int u0 = csr[i];
        f16x8 t0 = *(const f16x8*)(Hhi + (size_t)u0 * HD + cg * 8);
        a0 += (float)t0[0]; a1 += (float)t0[1]; a2 += (float)t0[2]; a3 += (float)t0[3];
        a4 += (float)t0[4]; a5 += (float)t0[5]; a6 += (float)t0[6]; a7 += (float)t0[7];
    }
    a0 += __shfl_down(a0, 32); a1 += __shfl_down(a1, 32);
    a2 += __shfl_down(a2, 32); a3 += __shfl_down(a3, 32);
    a4 += __shfl_down(a4, 32); a5 += __shfl_down(a5, 32);
    a6 += __shfl_down(a6, 32); a7 += __shfl_down(a7, 32);
    a0 += __shfl_down(a0, 16); a1 += __shfl_down(a1, 16);
    a2 += __shfl_down(a2, 16); a3 += __shfl_down(a3, 16);
    a4 += __shfl_down(a4, 16); a5 += __shfl_down(a5, 16);
    a6 += __shfl_down(a6, 16); a7 += __shfl_down(a7, 16);
    if (lane < 16) {
        f16x8 o;
        o[0] = (_Float16)a0; o[1] = (_Float16)a1; o[2] = (_Float16)a2; o[3] = (_Float16)a3;
        o[4] = (_Float16)a4; o[5] = (_Float16)a5; o[6] = (_Float16)a6; o[7] = (_Float16)a7;
        *(f16x8*)(Shi + (size_t)v * HD + cg * 8) = o;
    }
}

// ---------------- fused MFMA GEMM + GRU gates ----------------
// Block: 64 rows x 512 gate-cols, 4 waves split cols. A (S,Hhi,Hlo) staged via LDS
// (coalesced global 16B + XOR-swizzled ds_read_b128). B read as pre-swizzled contiguous
// 1KB fragments straight from L2. Epilogue: gates -> LDS -> coalesced 16B stores.
__global__ void __launch_bounds__(256, 2) k_ggemm(
        const _Float16* __restrict__ Shi,
        _Float16* __restrict__ Hhi, _Float16* __restrict__ Hlo,
        const _Float16* __restrict__ Bsw,
        const float* __restrict__ bih, const float* __restrict__ bhh) {
    __shared__ _Float16 Sl[64 * 128];    // S tile; reused as out-hi after phases
    __shared__ _Float16 Hh[64 * 128];
    __shared__ _Float16 Hl[64 * 128];
    __shared__ _Float16 Ol[64 * 128];    // out-lo
    int tid = threadIdx.x;
    int w = tid >> 6, lane = tid & 63;
    int quad = lane >> 4, l16 = lane & 15;
    int m0 = blockIdx.x * 64;

    // ---- stage A tiles (coalesced reads, swizzled LDS writes) ----
#pragma unroll
    for (int it = 0; it < 4; ++it) {
        int c = it * 256 + tid;          // 0..1023
        int row = c >> 4, kc = c & 15;
        int grow = m0 + row; if (grow >= NN) grow = NN - 1;
        size_t gsrc = (size_t)grow * HD + kc * 8;
        int ld = row * 128 + ((kc ^ (row & 15)) << 3);
        *(f16x8*)(&Sl[ld]) = *(const f16x8*)(Shi + gsrc);
        *(f16x8*)(&Hh[ld]) = *(const f16x8*)(Hhi + gsrc);
        *(f16x8*)(&Hl[ld]) = *(const f16x8*)(Hlo + gsrc);
    }
    __syncthreads();

    f32x4 acc[4][8];
#pragma unroll
    for (int mi = 0; mi < 4; ++mi)
#pragma unroll
        for (int t = 0; t < 8; ++t) acc[mi][t] = (f32x4){0.f, 0.f, 0.f, 0.f};

    // B fragment base: fragment (w,t,p) at Bsw + ((w*8+t)*8+p)*512, lane-contiguous 16B
    const _Float16* bw = Bsw + (size_t)(w * 8) * 8 * 512 + lane * 8;

    // Phases 0-3: A = S (1 product); gates r,z,i_n (t=0..5)
#pragma unroll
    for (int p = 0; p < 4; ++p) {
        f16x8 a[4];
#pragma unroll
        for (int mi = 0; mi < 4; ++mi)
            a[mi] = *(const f16x8*)(&Sl[lidx(mi * 16 + l16, p * 32 + quad * 8)]);
#pragma unroll
        for (int t = 0; t < 6; ++t) {
            f16x8 b = *(const f16x8*)(bw + (size_t)(t * 8 + p) * 512);
#pragma unroll
            for (int mi = 0; mi < 4; ++mi)
                acc[mi][t] = __builtin_amdgcn_mfma_f32_16x16x32_f16(a[mi], b, acc[mi][t], 0, 0, 0);
        }
    }

    // Phases 4-7: A = H hi/lo (2 products); gates r,z,h_n (t={0,1,2,3,6,7})
#pragma unroll
    for (int p = 0; p < 4; ++p) {
        f16x8 ah[4], al[4];
#pragma unroll
        for (int mi = 0; mi < 4; ++mi) {
            int li = lidx(mi * 16 + l16, p * 32 + quad * 8);
            ah[mi] = *(const f16x8*)(&Hh[li]);
            al[mi] = *(const f16x8*)(&Hl[li]);
        }
#pragma unroll
        for (int tt = 0; tt < 6; ++tt) {
            int t = (tt < 4) ? tt : (tt + 2);   // 0,1,2,3,6,7
            f16x8 b = *(const f16x8*)(bw + (size_t)(t * 8 + p + 4) * 512);
#pragma unroll
            for (int mi = 0; mi < 4; ++mi) {
                acc[mi][t] = __builtin_amdgcn_mfma_f32_16x16x32_f16(ah[mi], b, acc[mi][t], 0, 0, 0);
                acc[mi][t] = __builtin_amdgcn_mfma_f32_16x16x32_f16(al[mi], b, acc[mi][t], 0, 0, 0);
            }
        }
    }

    __syncthreads();   // S-LDS reads done; safe to reuse Sl as out-hi

    // ---- epilogue: gates; hold read from staged H-LDS; results to LDS ----
#pragma unroll
    for (int ns = 0; ns < 2; ++ns) {
        int j = w * 32 + ns * 16 + l16;
        float br  = bih[j]       + bhh[j];
        float bz  = bih[j + 128] + bhh[j + 128];
        float bin = bih[j + 256];
        float bhn = bhh[j + 256];
#pragma unroll
        for (int mi = 0; mi < 4; ++mi) {
#pragma unroll
            for (int reg = 0; reg < 4; ++reg) {
                int row = mi * 16 + quad * 4 + reg;   // block-local
                int li = lidx(row, j);
                float hold = (float)Hh[li] + (float)Hl[li];
                float r = sigm(acc[mi][0 + ns][reg] + br);
                float z = sigm(acc[mi][2 + ns][reg] + bz);
                float n = tanhfast(acc[mi][4 + ns][reg] + bin + r * (acc[mi][6 + ns][reg] + bhn));
                float hnew = (1.f - z) * n + z * hold;
                _Float16 hi = (_Float16)hnew;
                Sl[li] = hi;
                Ol[li] = (_Float16)(hnew - (float)hi);
            }
        }
    }
    __syncthreads();

    // ---- bulk coalesced store ----
#pragma unroll
    for (int it = 0; it < 4; ++it) {
        int c = it * 256 + tid;
        int row = c >> 4, kc = c & 15;
        int grow = m0 + row;
        if (grow < NN) {
            int ld = row * 128 + ((kc ^ (row & 15)) << 3);
            size_t gdst = (size_t)grow * HD + kc * 8;
            *(f16x8*)(Hhi + gdst) = *(const f16x8*)(&Sl[ld]);
            *(f16x8*)(Hlo + gdst) = *(const f16x8*)(&Ol[ld]);
        }
    }
}

// ---------------- pooling + head ----------------
__global__ void k_ginit(int* __restrict__ gs, int* __restrict__ ge) {
    int g = threadIdx.x;
    if (g < NG) { gs[g] = 0; ge[g] = 0; }
}

__global__ void k_bounds(const int* __restrict__ batch, int* __restrict__ gs, int* __restrict__ ge) {
    int i = blockIdx.x * 256 + threadIdx.x;
    if (i >= NN) return;
    int b = batch[i];
    if (i == 0 || batch[i - 1] != b) gs[b] = i;
    if (i == NN - 1 || batch[i + 1] != b) ge[b] = i + 1;
}

__global__ void k_pool(const _Float16* __restrict__ Hhi, const _Float16* __restrict__ Hlo,
                       const int* __restrict__ gs, const int* __restrict__ ge,
                       const float* __restrict__ Wp, const float* __restrict__ bp,
                       float* __restrict__ out) {
    __shared__ float red[HD];
    int g = blockIdx.x, tid = threadIdx.x;
    int s = gs[g], e = ge[g];
    float acc = 0.f;
    for (int n = s; n < e; ++n) {
        size_t idx = (size_t)n * HD + tid;
        acc += (float)Hhi[idx] + (float)Hlo[idx];
    }
    int cnt = e - s;
    float pooled = acc / (float)(cnt > 0 ? cnt : 1);
    red[tid] = fmaxf(pooled, 0.f) * Wp[tid];
    __syncthreads();
    for (int off = 64; off > 0; off >>= 1) {
        if (tid < off) red[tid] += red[tid + off];
        __syncthreads();
    }
    if (tid == 0) out[g] = red[0] + bp[0];
}

extern "C" void kernel_launch(void* const* d_in, const int* in_sizes, int n_in,
                              void* d_out, int out_size, void* d_ws, size_t ws_size,
                              hipStream_t stream) {
    const float* x   = (const float*)d_in[0];
    const int*   ei  = (const int*)d_in[1];
    const int*   bat = (const int*)d_in[2];
    const float* Win = (const float*)d_in[3];
    const float* Wmp = (const float*)d_in[4];
    const float* Wih = (const float*)d_in[5];
    const float* Whh = (const float*)d_in[6];
    const float* bih = (const float*)d_in[7];
    const float* bhh = (const float*)d_in[8];
    const float* Wp  = (const float*)d_in[9];
    const float* bp  = (const float*)d_in[10];
    float* out = (float*)d_out;

    const int* esrc = ei;
    const int* edst = ei + NE;

    char* w = (char*)d_ws;
    _Float16* Hhi = (_Float16*)w; w += (size_t)NN * HD * 2;
    _Float16* Hlo = (_Float16*)w; w += (size_t)NN * HD * 2;
    _Float16* Shi = (_Float16*)w; w += (size_t)NN * HD * 2;
    _Float16* Bsw = (_Float16*)w; w += (size_t)NSTEP * 131072 * 2;
    int* indptr  = (int*)w;   w += 400128;            // (NN+1)*4 padded
    int* cursor  = (int*)w;   w += 400128;
    int* csr     = (int*)w;   w += (size_t)NE * 4;
    int* aux     = (int*)w;   w += 512;
    int* gs      = (int*)w;   w += NG * 4;
    int* ge      = (int*)w;   w += NG * 4;

    // CSR build
    hipMemsetAsync(cursor, 0, (size_t)NN * 4, stream);
    k_count<<<NE / 256, 256, 0, stream>>>(edst, cursor);
    k_scan1<<<NBLK, 256, 0, stream>>>(cursor, indptr, aux);
    k_scan2<<<1, 128, 0, stream>>>(aux);
    k_scan3<<<NBLK, 256, 0, stream>>>(indptr, cursor, aux);
    k_fill<<<NE / 256, 256, 0, stream>>>(esrc, edst, cursor, csr);

    // weight prep + input layer
    k_prepB<<<NSTEP * 512, 256, 0, stream>>>(Wmp, Wih, Whh, Bsw);
    k_input<<<NN / 2, 256, 0, stream>>>(x, Win, Hhi, Hlo);

    // 6 message-passing + fused GEMM/GRU steps (H updated in place)
    for (int st = 0; st < NSTEP; ++st) {
        k_agg<<<NN / 4, 256, 0, stream>>>(Hhi, indptr, csr, Shi);
        k_ggemm<<<(NN + 63) / 64, 256, 0, stream>>>(Shi, Hhi, Hlo,
                                                    Bsw + (size_t)st * 131072,
                                                    bih, bhh);
    }

    // pooling + head
    k_ginit<<<1, NG, 0, stream>>>(gs, ge);
    k_bounds<<<(NN + 255) / 256, 256, 0, stream>>>(bat, gs, ge);
    k_pool<<<NG, HD, 0, stream>>>(Hhi, Hlo, gs, ge, Wp, bp, out);
}